// Round 2
// baseline (1825.253 us; speedup 1.0000x reference)
//
#include <hip/hip_runtime.h>
#include <math.h>

#define NNODES 100000
#define NEDGES 1600000
#define FD 128
#define NCLS 40

// ---------------- edge_index dtype detection (int64 vs harness-narrowed int32) -------------
// Sample E/4096-strided int64 slots from the first E slots (in-bounds under BOTH layouts:
// int64 buffer has 2E slots; int32 buffer has E int64-slots' worth of bytes).
// int64 layout: every slot is a valid src index in [0,N). int32 layout: slot = lo|hi<<32 with
// hi a dst-half... (any nonzero hi word -> out of range). P(all 4096 samples look valid) ~ 0.

__global__ void detect_kernel(const long long* __restrict__ ei, int* __restrict__ flag_is32) {
    int t = blockIdx.x * blockDim.x + threadIdx.x;      // 4096 threads
    size_t idx = (size_t)t * (NEDGES / 4096);           // < NEDGES
    long long v = ei[idx];
    if (v < 0 || v >= NNODES) atomicOr(flag_is32, 1);
}

__device__ __forceinline__ void load_edge(const void* eiv, int is32, int e, int& s, int& d) {
    if (is32) {
        const int* p = (const int*)eiv;
        s = p[e]; d = p[NEDGES + e];
    } else {
        const long long* p = (const long long*)eiv;
        s = (int)p[e]; d = (int)p[NEDGES + e];
    }
}

// ---------------- CSR build (dst-sorted adjacency), built once per call ----------------

__global__ void hist_kernel(const void* __restrict__ eiv, const int* __restrict__ flag_is32,
                            int* __restrict__ row_ptr) {
    int is32 = *flag_is32;
    int e = blockIdx.x * blockDim.x + threadIdx.x;
    if (e < NEDGES) {
        int s, d;
        load_edge(eiv, is32, e, s, d);
        atomicAdd(&row_ptr[d + 1], 1);
    }
}

__global__ __launch_bounds__(1024) void scan_kernel(int* __restrict__ row_ptr, int* __restrict__ cursor) {
    // single-block scan over NNODES counts
    __shared__ int wtot[16];
    __shared__ int woff[16];
    __shared__ int running_s;
    int t = threadIdx.x;
    int lane = t & 63, wid = t >> 6;
    if (t == 0) running_s = 0;
    __syncthreads();
    for (int base = 0; base < NNODES; base += 1024) {
        int i = base + t;
        int c = (i < NNODES) ? row_ptr[1 + i] : 0;
        int x = c;
        #pragma unroll
        for (int off = 1; off < 64; off <<= 1) {
            int y = __shfl_up(x, off, 64);
            if (lane >= off) x += y;
        }
        if (lane == 63) wtot[wid] = x;
        __syncthreads();
        if (t < 16) {
            int v = wtot[t];
            #pragma unroll
            for (int off = 1; off < 16; off <<= 1) {
                int y = __shfl_up(v, off, 64);
                if (t >= off) v += y;
            }
            woff[t] = v;
        }
        __syncthreads();
        int excl = (wid == 0) ? 0 : woff[wid - 1];
        int incl = x + excl;
        int run = running_s;
        int total = woff[15];
        if (i < NNODES) {
            row_ptr[1 + i] = run + incl;       // inclusive prefix -> row_ptr[i+1]
            cursor[i]      = run + incl - c;   // exclusive prefix -> fill cursor
        }
        __syncthreads();
        if (t == 0) running_s = run + total;
        __syncthreads();
    }
}

__global__ void fill_kernel(const void* __restrict__ eiv, const int* __restrict__ flag_is32,
                            int* __restrict__ cursor, int* __restrict__ src_sorted) {
    int is32 = *flag_is32;
    int e = blockIdx.x * blockDim.x + threadIdx.x;
    if (e < NEDGES) {
        int s, d;
        load_edge(eiv, is32, e, s, d);
        int pos = atomicAdd(&cursor[d], 1);
        src_sorted[pos] = s;
    }
}

// ---------------- fused 4-projection GEMM: Y{0..3} = X @ W{0..3} + b{0..3} ----------------
// X: [NNODES][128] fp32. Each W: [128][128]. grid = (ceil(N/64), 8); blockIdx.y -> (proj, col-half)
// Intra-wave LDS conflict check: a wave spans 4 ty values -> A-reads are 4 broadcast
// addresses (<=2 banks, 2-way=free); B-reads 16 addrs at 16B stride (2-way). Pad 68 kept.

__global__ __launch_bounds__(256) void proj_gemm(
    const float* __restrict__ X,
    const float* __restrict__ W0, const float* __restrict__ b0, float* __restrict__ Y0,
    const float* __restrict__ W1, const float* __restrict__ b1, float* __restrict__ Y1,
    const float* __restrict__ W2, const float* __restrict__ b2, float* __restrict__ Y2,
    const float* __restrict__ W3, const float* __restrict__ b3, float* __restrict__ Y3)
{
    __shared__ float As[64][68];
    __shared__ float Bs[64][68];
    int t = threadIdx.x;
    int tx = t & 15, ty = t >> 4;
    int ct = blockIdx.y;                  // 0..7
    int proj = ct >> 1;
    int colbase = (ct & 1) * 64;
    const float* W    = (proj == 0) ? W0 : (proj == 1) ? W1 : (proj == 2) ? W2 : W3;
    const float* bias = (proj == 0) ? b0 : (proj == 1) ? b1 : (proj == 2) ? b2 : b3;
    float*       Y    = (proj == 0) ? Y0 : (proj == 1) ? Y1 : (proj == 2) ? Y2 : Y3;
    int rowbase = blockIdx.x * 64;

    float4 acc0 = make_float4(0.f, 0.f, 0.f, 0.f);
    float4 acc1 = acc0, acc2 = acc0, acc3 = acc0;

    for (int kt = 0; kt < 2; kt++) {
        #pragma unroll
        for (int i = 0; i < 4; i++) {
            int idx = t + i * 256;
            int r = idx >> 4, c4 = idx & 15;
            int rg = rowbase + r;
            float4 v = make_float4(0.f, 0.f, 0.f, 0.f);
            if (rg < NNODES) v = *(const float4*)(X + (size_t)rg * FD + kt * 64 + c4 * 4);
            *(float4*)&As[r][c4 * 4] = v;
        }
        #pragma unroll
        for (int i = 0; i < 4; i++) {
            int idx = t + i * 256;
            int k = idx >> 4, c4 = idx & 15;
            float4 v = *(const float4*)(W + (size_t)(kt * 64 + k) * FD + colbase + c4 * 4);
            *(float4*)&Bs[k][c4 * 4] = v;
        }
        __syncthreads();

        #pragma unroll
        for (int k4 = 0; k4 < 16; k4++) {
            float4 a0 = *(float4*)&As[ty * 4 + 0][k4 * 4];
            float4 a1 = *(float4*)&As[ty * 4 + 1][k4 * 4];
            float4 a2 = *(float4*)&As[ty * 4 + 2][k4 * 4];
            float4 a3 = *(float4*)&As[ty * 4 + 3][k4 * 4];
            float4 bq0 = *(float4*)&Bs[k4 * 4 + 0][tx * 4];
            float4 bq1 = *(float4*)&Bs[k4 * 4 + 1][tx * 4];
            float4 bq2 = *(float4*)&Bs[k4 * 4 + 2][tx * 4];
            float4 bq3 = *(float4*)&Bs[k4 * 4 + 3][tx * 4];
#define MAD_ROW(ACC, A)                                              \
            ACC.x += A.x * bq0.x + A.y * bq1.x + A.z * bq2.x + A.w * bq3.x; \
            ACC.y += A.x * bq0.y + A.y * bq1.y + A.z * bq2.y + A.w * bq3.y; \
            ACC.z += A.x * bq0.z + A.y * bq1.z + A.z * bq2.z + A.w * bq3.z; \
            ACC.w += A.x * bq0.w + A.y * bq1.w + A.z * bq2.w + A.w * bq3.w;
            MAD_ROW(acc0, a0)
            MAD_ROW(acc1, a1)
            MAD_ROW(acc2, a2)
            MAD_ROW(acc3, a3)
#undef MAD_ROW
        }
        __syncthreads();
    }

    float4 bb = *(const float4*)(bias + colbase + tx * 4);
    acc0.x += bb.x; acc0.y += bb.y; acc0.z += bb.z; acc0.w += bb.w;
    acc1.x += bb.x; acc1.y += bb.y; acc1.z += bb.z; acc1.w += bb.w;
    acc2.x += bb.x; acc2.y += bb.y; acc2.z += bb.z; acc2.w += bb.w;
    acc3.x += bb.x; acc3.y += bb.y; acc3.z += bb.z; acc3.w += bb.w;

    float4 accs[4] = {acc0, acc1, acc2, acc3};
    #pragma unroll
    for (int i = 0; i < 4; i++) {
        int rg = rowbase + ty * 4 + i;
        if (rg < NNODES)
            *(float4*)(Y + (size_t)rg * FD + colbase + tx * 4) = accs[i];
    }
}

// ---------------- per-node online-softmax aggregation (one wave per dst node) ----------------
// lane l owns feature elems 2l, 2l+1 ; head = elem/64 -> lanes 0..31 = head0, 32..63 = head1

__global__ __launch_bounds__(256) void agg_kernel(
    const float* __restrict__ Q, const float* __restrict__ K, const float* __restrict__ V,
    const float* __restrict__ SKIP, float* __restrict__ OUT,
    const int* __restrict__ row_ptr, const int* __restrict__ src_sorted, int apply_elu)
{
    int wid  = threadIdx.x >> 6;
    int lane = threadIdx.x & 63;
    int node = blockIdx.x * 4 + wid;
    if (node >= NNODES) return;
    size_t rb = (size_t)node * FD;
    float2 q = *(const float2*)(Q + rb + 2 * lane);
    q.x *= 0.125f; q.y *= 0.125f;          // 1/sqrt(64)
    float m = -INFINITY, s = 0.f;
    float accx = 0.f, accy = 0.f;
    int e0 = row_ptr[node], e1 = row_ptr[node + 1];
    for (int e = e0; e < e1; e++) {
        int j = src_sorted[e];
        size_t jb = (size_t)j * FD;
        float2 kk = *(const float2*)(K + jb + 2 * lane);
        float2 vv = *(const float2*)(V + jb + 2 * lane);
        float p = q.x * kk.x + q.y * kk.y;
        p += __shfl_xor(p, 1, 64);
        p += __shfl_xor(p, 2, 64);
        p += __shfl_xor(p, 4, 64);
        p += __shfl_xor(p, 8, 64);
        p += __shfl_xor(p, 16, 64);        // per-32-lane-half sum = this head's alpha
        float mn   = fmaxf(m, p);
        float corr = __expf(m - mn);       // expf(-inf)=0 handles first edge
        float w    = __expf(p - mn);
        s    = s * corr + w;
        accx = accx * corr + w * vv.x;
        accy = accy * corr + w * vv.y;
        m = mn;
    }
    float r = 1.f / (s + 1e-16f);
    float2 sk = *(const float2*)(SKIP + rb + 2 * lane);
    float ox = accx * r + sk.x;
    float oy = accy * r + sk.y;
    if (apply_elu) {
        ox = (ox > 0.f) ? ox : (__expf(ox) - 1.f);
        oy = (oy > 0.f) ? oy : (__expf(oy) - 1.f);
    }
    *(float2*)(OUT + rb + 2 * lane) = make_float2(ox, oy);
}

// ---------------- final classifier: out = H @ Wlin + blin  ([N,128] @ [128,40]) ----------------

__global__ void final_lin(const float* __restrict__ H, const float* __restrict__ Wl,
                          const float* __restrict__ bl, float* __restrict__ out)
{
    __shared__ float ws[FD * NCLS];    // 20 KB
    __shared__ float xs[8][FD + 1];
    int tx = threadIdx.x;              // 0..39 (col)
    int ty = threadIdx.y;              // 0..7  (row)
    int t = ty * NCLS + tx;            // 0..319
    for (int i = t; i < FD * NCLS; i += 320) ws[i] = Wl[i];
    int row = blockIdx.x * 8;
    for (int i = t; i < 8 * FD; i += 320) {
        int r = i >> 7, c = i & 127;
        xs[r][c] = (row + r < NNODES) ? H[(size_t)(row + r) * FD + c] : 0.f;
    }
    __syncthreads();
    float acc = bl[tx];
    #pragma unroll
    for (int k = 0; k < FD; k++) acc += xs[ty][k] * ws[k * NCLS + tx];
    if (row + ty < NNODES) out[(size_t)(row + ty) * NCLS + tx] = acc;
}

// ---------------- launch ----------------

extern "C" void kernel_launch(void* const* d_in, const int* in_sizes, int n_in,
                              void* d_out, int out_size, void* d_ws, size_t ws_size,
                              hipStream_t stream) {
    const float* x  = (const float*)d_in[0];
    const void*  ei = d_in[1];                      // int64 or int32 — detected on device
    const float* Wq1 = (const float*)d_in[2],  *bq1 = (const float*)d_in[3];
    const float* Wk1 = (const float*)d_in[4],  *bk1 = (const float*)d_in[5];
    const float* Wv1 = (const float*)d_in[6],  *bv1 = (const float*)d_in[7];
    const float* Ws1 = (const float*)d_in[8],  *bs1 = (const float*)d_in[9];
    const float* Wq2 = (const float*)d_in[10], *bq2 = (const float*)d_in[11];
    const float* Wk2 = (const float*)d_in[12], *bk2 = (const float*)d_in[13];
    const float* Wv2 = (const float*)d_in[14], *bv2 = (const float*)d_in[15];
    const float* Ws2 = (const float*)d_in[16], *bs2 = (const float*)d_in[17];
    const float* Wlin = (const float*)d_in[18], *blin = (const float*)d_in[19];
    float* out = (float*)d_out;

    const size_t BUFE = (size_t)NNODES * FD;        // 12.8M floats
    float* Bb = (float*)d_ws;                       // layer buffers B..F
    float* Cb = Bb + BUFE;
    float* Db = Cb + BUFE;
    float* Eb = Db + BUFE;
    float* Fb = Eb + BUFE;
    int* row_ptr    = (int*)(Fb + BUFE);            // N+1
    int* cursor     = row_ptr + (NNODES + 1);       // N
    int* src_sorted = cursor + NNODES;              // E
    int* flag_is32  = src_sorted + NEDGES;          // 1

    // ---- dtype detect + CSR build (edge_index shared by both layers) ----
    hipMemsetAsync(row_ptr, 0, (NNODES + 1) * sizeof(int), stream);
    hipMemsetAsync(flag_is32, 0, sizeof(int), stream);
    detect_kernel<<<16, 256, 0, stream>>>((const long long*)ei, flag_is32);
    hist_kernel<<<(NEDGES + 255) / 256, 256, 0, stream>>>(ei, flag_is32, row_ptr);
    scan_kernel<<<1, 1024, 0, stream>>>(row_ptr, cursor);
    fill_kernel<<<(NEDGES + 255) / 256, 256, 0, stream>>>(ei, flag_is32, cursor, src_sorted);

    dim3 ggrid((NNODES + 63) / 64, 8);

    // ---- layer 1 ----
    proj_gemm<<<ggrid, 256, 0, stream>>>(x,
        Wq1, bq1, Bb,  Wk1, bk1, Cb,  Wv1, bv1, Db,  Ws1, bs1, Eb);
    agg_kernel<<<(NNODES + 3) / 4, 256, 0, stream>>>(Bb, Cb, Db, Eb, Bb,
        row_ptr, src_sorted, 1);

    // ---- layer 2 ----
    proj_gemm<<<ggrid, 256, 0, stream>>>(Bb,
        Wq2, bq2, Cb,  Wk2, bk2, Db,  Wv2, bv2, Eb,  Ws2, bs2, Fb);
    agg_kernel<<<(NNODES + 3) / 4, 256, 0, stream>>>(Cb, Db, Eb, Fb, Cb,
        row_ptr, src_sorted, 0);

    // ---- classifier ----
    final_lin<<<(NNODES + 7) / 8, dim3(NCLS, 8), 0, stream>>>(Cb, Wlin, blin, out);
}

// Round 4
// 1266.225 us; speedup vs baseline: 1.4415x; 1.4415x over previous
//
#include <hip/hip_runtime.h>
#include <math.h>

#define NNODES 100000
#define NEDGES 1600000
#define FD 128
#define NCLS 40

typedef __attribute__((ext_vector_type(8))) short short8v;   // 8 x bf16 (4 VGPR)
typedef __attribute__((ext_vector_type(4))) float f32x4;

__device__ __forceinline__ unsigned short f32_to_bf16_rne(float f) {
    unsigned int u = __float_as_uint(f);
    unsigned int r = u + 0x7fff + ((u >> 16) & 1);
    return (unsigned short)(r >> 16);
}
__device__ __forceinline__ float bf16_to_f32(unsigned short h) {
    return __uint_as_float(((unsigned int)h) << 16);
}

// ---------------- edge_index dtype detection (int64 vs harness-narrowed int32) -------------

__global__ void detect_kernel(const long long* __restrict__ ei, int* __restrict__ flag_is32) {
    int t = blockIdx.x * blockDim.x + threadIdx.x;      // 4096 threads
    size_t idx = (size_t)t * (NEDGES / 4096);           // < NEDGES
    long long v = ei[idx];
    if (v < 0 || v >= NNODES) atomicOr(flag_is32, 1);
}

__device__ __forceinline__ void load_edge(const void* eiv, int is32, int e, int& s, int& d) {
    if (is32) {
        const int* p = (const int*)eiv;
        s = p[e]; d = p[NEDGES + e];
    } else {
        const long long* p = (const long long*)eiv;
        s = (int)p[e]; d = (int)p[NEDGES + e];
    }
}

// ---------------- CSR build (dst-sorted adjacency), built once per call ----------------

__global__ void hist_kernel(const void* __restrict__ eiv, const int* __restrict__ flag_is32,
                            int* __restrict__ row_ptr) {
    int is32 = *flag_is32;
    int e = blockIdx.x * blockDim.x + threadIdx.x;
    if (e < NEDGES) {
        int s, d;
        load_edge(eiv, is32, e, s, d);
        atomicAdd(&row_ptr[d + 1], 1);
    }
}

__global__ __launch_bounds__(1024) void scan_kernel(int* __restrict__ row_ptr, int* __restrict__ cursor) {
    __shared__ int wtot[16];
    __shared__ int woff[16];
    __shared__ int running_s;
    int t = threadIdx.x;
    int lane = t & 63, wid = t >> 6;
    if (t == 0) running_s = 0;
    __syncthreads();
    for (int base = 0; base < NNODES; base += 1024) {
        int i = base + t;
        int c = (i < NNODES) ? row_ptr[1 + i] : 0;
        int x = c;
        #pragma unroll
        for (int off = 1; off < 64; off <<= 1) {
            int y = __shfl_up(x, off, 64);
            if (lane >= off) x += y;
        }
        if (lane == 63) wtot[wid] = x;
        __syncthreads();
        if (t < 16) {
            int v = wtot[t];
            #pragma unroll
            for (int off = 1; off < 16; off <<= 1) {
                int y = __shfl_up(v, off, 64);
                if (t >= off) v += y;
            }
            woff[t] = v;
        }
        __syncthreads();
        int excl = (wid == 0) ? 0 : woff[wid - 1];
        int incl = x + excl;
        int run = running_s;
        int total = woff[15];
        if (i < NNODES) {
            row_ptr[1 + i] = run + incl;
            cursor[i]      = run + incl - c;
        }
        __syncthreads();
        if (t == 0) running_s = run + total;
        __syncthreads();
    }
}

__global__ void fill_kernel(const void* __restrict__ eiv, const int* __restrict__ flag_is32,
                            int* __restrict__ cursor, int* __restrict__ src_sorted) {
    int is32 = *flag_is32;
    int e = blockIdx.x * blockDim.x + threadIdx.x;
    if (e < NEDGES) {
        int s, d;
        load_edge(eiv, is32, e, s, d);
        int pos = atomicAdd(&cursor[d], 1);
        src_sorted[pos] = s;
    }
}

// ---------------- W pack: fp32 [128][128] -> MFMA-frag-ordered bf16 hi/lo ----------------
// packed[slot][ct][kk][lane][j] = W[kk*32 + (lane>>4)*8 + j][ct*16 + (lane&15)]
// slot = 0..7 (Wq1,Wk1,Wv1,Ws1,Wq2,Wk2,Wv2,Ws2). 16384 bf16 per slot per hi/lo.

__global__ void pack_w(const float* __restrict__ W, short* __restrict__ Whi,
                       short* __restrict__ Wlo, int slot) {
    int lane = threadIdx.x;            // 64
    int ctkk = blockIdx.x;             // 32: ct*4+kk
    int ct = ctkk >> 2, kk = ctkk & 3;
    int col = ct * 16 + (lane & 15);
    int k0 = kk * 32 + (lane >> 4) * 8;
    short8v h, l;
    #pragma unroll
    for (int j = 0; j < 8; j++) {
        float v = W[(size_t)(k0 + j) * FD + col];
        unsigned short hh = f32_to_bf16_rne(v);
        float rem = v - bf16_to_f32(hh);
        h[j] = (short)hh;
        l[j] = (short)f32_to_bf16_rne(rem);
    }
    size_t o = ((size_t)slot * 32 + ctkk) * 512 + (size_t)lane * 8;
    *(short8v*)(Whi + o) = h;
    *(short8v*)(Wlo + o) = l;
}

// ---------------- fused 4-projection GEMM via bf16 MFMA, fp32-split 3-pass ----------------
// block = 256 (4 waves); wave owns 16 rows, loops 4 proj x 8 col-tiles. No LDS.
// A-frags in registers (hi/lo), B-frags from packed W (coalesced 16B, L1/L2-resident).

__global__ __launch_bounds__(256) void proj_gemm_mfma(
    const float* __restrict__ X,
    const short* __restrict__ Whi, const short* __restrict__ Wlo,   // layer base (4 slots)
    const float* __restrict__ b0, const float* __restrict__ b1,
    const float* __restrict__ b2, const float* __restrict__ b3,
    float* __restrict__ Y0, float* __restrict__ Y1,
    float* __restrict__ Y2, float* __restrict__ Y3)
{
    int wid = threadIdx.x >> 6, lane = threadIdx.x & 63;
    int rowbase = blockIdx.x * 64 + wid * 16;
    int r = lane & 15, q = lane >> 4;
    int row = rowbase + r;

    short8v xh[4], xl[4];
    if (row < NNODES) {
        const float* xp = X + (size_t)row * FD + q * 8;
        #pragma unroll
        for (int kk = 0; kk < 4; kk++) {
            float4 v0 = *(const float4*)(xp + kk * 32);
            float4 v1 = *(const float4*)(xp + kk * 32 + 4);
            float vv[8] = {v0.x, v0.y, v0.z, v0.w, v1.x, v1.y, v1.z, v1.w};
            #pragma unroll
            for (int j = 0; j < 8; j++) {
                unsigned short h = f32_to_bf16_rne(vv[j]);
                float rem = vv[j] - bf16_to_f32(h);
                xh[kk][j] = (short)h;
                xl[kk][j] = (short)f32_to_bf16_rne(rem);
            }
        }
    } else {
        short8v z = {0, 0, 0, 0, 0, 0, 0, 0};
        #pragma unroll
        for (int kk = 0; kk < 4; kk++) { xh[kk] = z; xl[kk] = z; }
    }

    #pragma unroll
    for (int pt = 0; pt < 4; pt++) {
        const float* bias = (pt == 0) ? b0 : (pt == 1) ? b1 : (pt == 2) ? b2 : b3;
        float*       Y    = (pt == 0) ? Y0 : (pt == 1) ? Y1 : (pt == 2) ? Y2 : Y3;
        #pragma unroll
        for (int ct = 0; ct < 8; ct++) {
            const short* wp = Whi + ((size_t)(pt * 8 + ct) * 4) * 512 + (size_t)lane * 8;
            const short* lp = Wlo + ((size_t)(pt * 8 + ct) * 4) * 512 + (size_t)lane * 8;
            f32x4 acc = {0.f, 0.f, 0.f, 0.f};
            #pragma unroll
            for (int kk = 0; kk < 4; kk++) {
                short8v bh = *(const short8v*)(wp + kk * 512);
                short8v bl = *(const short8v*)(lp + kk * 512);
                acc = __builtin_amdgcn_mfma_f32_16x16x32_bf16(xh[kk], bh, acc, 0, 0, 0);
                acc = __builtin_amdgcn_mfma_f32_16x16x32_bf16(xl[kk], bh, acc, 0, 0, 0);
                acc = __builtin_amdgcn_mfma_f32_16x16x32_bf16(xh[kk], bl, acc, 0, 0, 0);
            }
            float bb = bias[ct * 16 + r];
            #pragma unroll
            for (int j = 0; j < 4; j++) {
                int ro = rowbase + q * 4 + j;          // D: col=lane&15, row=(lane>>4)*4+j
                if (ro < NNODES)
                    Y[(size_t)ro * FD + ct * 16 + r] = acc[j] + bb;
            }
        }
    }
}

// ---------------- per-node online-softmax aggregation (one wave per dst node) ----------------

__global__ __launch_bounds__(256) void agg_kernel(
    const float* __restrict__ Q, const float* __restrict__ K, const float* __restrict__ V,
    const float* __restrict__ SKIP, float* __restrict__ OUT,
    const int* __restrict__ row_ptr, const int* __restrict__ src_sorted, int apply_elu)
{
    int wid  = threadIdx.x >> 6;
    int lane = threadIdx.x & 63;
    int node = blockIdx.x * 4 + wid;
    if (node >= NNODES) return;
    size_t rb = (size_t)node * FD;
    float2 q = *(const float2*)(Q + rb + 2 * lane);
    q.x *= 0.125f; q.y *= 0.125f;          // 1/sqrt(64)
    float m = -INFINITY, s = 0.f;
    float accx = 0.f, accy = 0.f;
    int e0 = row_ptr[node], e1 = row_ptr[node + 1];
    for (int e = e0; e < e1; e++) {
        int j = src_sorted[e];
        size_t jb = (size_t)j * FD;
        float2 kk = *(const float2*)(K + jb + 2 * lane);
        float2 vv = *(const float2*)(V + jb + 2 * lane);
        float p = q.x * kk.x + q.y * kk.y;
        p += __shfl_xor(p, 1, 64);
        p += __shfl_xor(p, 2, 64);
        p += __shfl_xor(p, 4, 64);
        p += __shfl_xor(p, 8, 64);
        p += __shfl_xor(p, 16, 64);        // per-32-lane-half sum = this head's alpha
        float mn   = fmaxf(m, p);
        float corr = __expf(m - mn);
        float w    = __expf(p - mn);
        s    = s * corr + w;
        accx = accx * corr + w * vv.x;
        accy = accy * corr + w * vv.y;
        m = mn;
    }
    float r = 1.f / (s + 1e-16f);
    float2 sk = *(const float2*)(SKIP + rb + 2 * lane);
    float ox = accx * r + sk.x;
    float oy = accy * r + sk.y;
    if (apply_elu) {
        ox = (ox > 0.f) ? ox : (__expf(ox) - 1.f);
        oy = (oy > 0.f) ? oy : (__expf(oy) - 1.f);
    }
    *(float2*)(OUT + rb + 2 * lane) = make_float2(ox, oy);
}

// ---------------- final classifier: out = H @ Wlin + blin  ([N,128] @ [128,40]) ----------------

__global__ void final_lin(const float* __restrict__ H, const float* __restrict__ Wl,
                          const float* __restrict__ bl, float* __restrict__ out)
{
    __shared__ float ws[FD * NCLS];    // 20 KB
    __shared__ float xs[8][FD + 1];
    int tx = threadIdx.x;              // 0..39 (col)
    int ty = threadIdx.y;              // 0..7  (row)
    int t = ty * NCLS + tx;
    for (int i = t; i < FD * NCLS; i += 320) ws[i] = Wl[i];
    int row = blockIdx.x * 8;
    for (int i = t; i < 8 * FD; i += 320) {
        int r = i >> 7, c = i & 127;
        xs[r][c] = (row + r < NNODES) ? H[(size_t)(row + r) * FD + c] : 0.f;
    }
    __syncthreads();
    float acc = bl[tx];
    #pragma unroll
    for (int k = 0; k < FD; k++) acc += xs[ty][k] * ws[k * NCLS + tx];
    if (row + ty < NNODES) out[(size_t)(row + ty) * NCLS + tx] = acc;
}

// ---------------- launch ----------------

extern "C" void kernel_launch(void* const* d_in, const int* in_sizes, int n_in,
                              void* d_out, int out_size, void* d_ws, size_t ws_size,
                              hipStream_t stream) {
    const float* x  = (const float*)d_in[0];
    const void*  ei = d_in[1];
    const float* Wq1 = (const float*)d_in[2],  *bq1 = (const float*)d_in[3];
    const float* Wk1 = (const float*)d_in[4],  *bk1 = (const float*)d_in[5];
    const float* Wv1 = (const float*)d_in[6],  *bv1 = (const float*)d_in[7];
    const float* Ws1 = (const float*)d_in[8],  *bs1 = (const float*)d_in[9];
    const float* Wq2 = (const float*)d_in[10], *bq2 = (const float*)d_in[11];
    const float* Wk2 = (const float*)d_in[12], *bk2 = (const float*)d_in[13];
    const float* Wv2 = (const float*)d_in[14], *bv2 = (const float*)d_in[15];
    const float* Ws2 = (const float*)d_in[16], *bs2 = (const float*)d_in[17];
    const float* Wlin = (const float*)d_in[18], *blin = (const float*)d_in[19];
    float* out = (float*)d_out;

    const size_t BUFE = (size_t)NNODES * FD;
    float* Bb = (float*)d_ws;
    float* Cb = Bb + BUFE;
    float* Db = Cb + BUFE;
    float* Eb = Db + BUFE;
    float* Fb = Eb + BUFE;
    int* row_ptr    = (int*)(Fb + BUFE);            // N+1
    int* cursor     = row_ptr + (NNODES + 1);       // N
    int* src_sorted = cursor + NNODES;              // E
    int* flag_is32  = src_sorted + NEDGES;          // 1
    uintptr_t pal = ((uintptr_t)(flag_is32 + 1) + 15) & ~(uintptr_t)15;
    short* Whi = (short*)pal;                       // 8 slots x 16384 bf16 = 256 KB
    short* Wlo = Whi + 8 * 16384;

    // ---- weight packing (tiny) ----
    const float* Ws[8] = {Wq1, Wk1, Wv1, Ws1, Wq2, Wk2, Wv2, Ws2};
    for (int s = 0; s < 8; s++)
        pack_w<<<32, 64, 0, stream>>>(Ws[s], Whi, Wlo, s);

    // ---- dtype detect + CSR build ----
    hipMemsetAsync(row_ptr, 0, (NNODES + 1) * sizeof(int), stream);
    hipMemsetAsync(flag_is32, 0, sizeof(int), stream);
    detect_kernel<<<16, 256, 0, stream>>>((const long long*)ei, flag_is32);
    hist_kernel<<<(NEDGES + 255) / 256, 256, 0, stream>>>(ei, flag_is32, row_ptr);
    scan_kernel<<<1, 1024, 0, stream>>>(row_ptr, cursor);
    fill_kernel<<<(NEDGES + 255) / 256, 256, 0, stream>>>(ei, flag_is32, cursor, src_sorted);

    int pgrid = (NNODES + 63) / 64;

    // ---- layer 1 ----
    proj_gemm_mfma<<<pgrid, 256, 0, stream>>>(x, Whi, Wlo,
        bq1, bk1, bv1, bs1, Bb, Cb, Db, Eb);
    agg_kernel<<<(NNODES + 3) / 4, 256, 0, stream>>>(Bb, Cb, Db, Eb, Bb,
        row_ptr, src_sorted, 1);

    // ---- layer 2 ----
    proj_gemm_mfma<<<pgrid, 256, 0, stream>>>(Bb, Whi + 4 * 16384, Wlo + 4 * 16384,
        bq2, bk2, bv2, bs2, Cb, Db, Eb, Fb);
    agg_kernel<<<(NNODES + 3) / 4, 256, 0, stream>>>(Cb, Db, Eb, Fb, Cb,
        row_ptr, src_sorted, 0);

    // ---- classifier ----
    final_lin<<<(NNODES + 7) / 8, dim3(NCLS, 8), 0, stream>>>(Cb, Wlin, blin, out);
}

// Round 6
// 1192.121 us; speedup vs baseline: 1.5311x; 1.0622x over previous
//
#include <hip/hip_runtime.h>
#include <math.h>

#define NNODES 100000
#define NEDGES 1600000
#define FD 128
#define NCLS 40

typedef __attribute__((ext_vector_type(8))) short short8v;   // 8 x bf16 (4 VGPR)
typedef __attribute__((ext_vector_type(4))) float f32x4;

__device__ __forceinline__ unsigned short f32_to_bf16_rne(float f) {
    unsigned int u = __float_as_uint(f);
    unsigned int r = u + 0x7fff + ((u >> 16) & 1);
    return (unsigned short)(r >> 16);
}
__device__ __forceinline__ float bf16_to_f32(unsigned short h) {
    return __uint_as_float(((unsigned int)h) << 16);
}

// ---------------- edge_index dtype detection (int64 vs harness-narrowed int32) -------------

__global__ void detect_kernel(const long long* __restrict__ ei, int* __restrict__ flag_is32) {
    int t = blockIdx.x * blockDim.x + threadIdx.x;      // 4096 threads
    size_t idx = (size_t)t * (NEDGES / 4096);           // < NEDGES
    long long v = ei[idx];
    if (v < 0 || v >= NNODES) atomicOr(flag_is32, 1);
}

__device__ __forceinline__ void load_edge(const void* eiv, int is32, int e, int& s, int& d) {
    if (is32) {
        const int* p = (const int*)eiv;
        s = p[e]; d = p[NEDGES + e];
    } else {
        const long long* p = (const long long*)eiv;
        s = (int)p[e]; d = (int)p[NEDGES + e];
    }
}

// ---------------- CSR build (dst-sorted adjacency), built once per call ----------------

__global__ void hist_kernel(const void* __restrict__ eiv, const int* __restrict__ flag_is32,
                            int* __restrict__ row_ptr) {
    int is32 = *flag_is32;
    int e = blockIdx.x * blockDim.x + threadIdx.x;
    if (e < NEDGES) {
        int s, d;
        load_edge(eiv, is32, e, s, d);
        atomicAdd(&row_ptr[d + 1], 1);
    }
}

__global__ __launch_bounds__(1024) void scan_kernel(int* __restrict__ row_ptr, int* __restrict__ cursor) {
    __shared__ int wtot[16];
    __shared__ int woff[16];
    __shared__ int running_s;
    int t = threadIdx.x;
    int lane = t & 63, wid = t >> 6;
    if (t == 0) running_s = 0;
    __syncthreads();
    for (int base = 0; base < NNODES; base += 1024) {
        int i = base + t;
        int c = (i < NNODES) ? row_ptr[1 + i] : 0;
        int x = c;
        #pragma unroll
        for (int off = 1; off < 64; off <<= 1) {
            int y = __shfl_up(x, off, 64);
            if (lane >= off) x += y;
        }
        if (lane == 63) wtot[wid] = x;
        __syncthreads();
        if (t < 16) {
            int v = wtot[t];
            #pragma unroll
            for (int off = 1; off < 16; off <<= 1) {
                int y = __shfl_up(v, off, 64);
                if (t >= off) v += y;
            }
            woff[t] = v;
        }
        __syncthreads();
        int excl = (wid == 0) ? 0 : woff[wid - 1];
        int incl = x + excl;
        int run = running_s;
        int total = woff[15];
        if (i < NNODES) {
            row_ptr[1 + i] = run + incl;
            cursor[i]      = run + incl - c;
        }
        __syncthreads();
        if (t == 0) running_s = run + total;
        __syncthreads();
    }
}

__global__ void fill_kernel(const void* __restrict__ eiv, const int* __restrict__ flag_is32,
                            int* __restrict__ cursor, int* __restrict__ src_sorted) {
    int is32 = *flag_is32;
    int e = blockIdx.x * blockDim.x + threadIdx.x;
    if (e < NEDGES) {
        int s, d;
        load_edge(eiv, is32, e, s, d);
        int pos = atomicAdd(&cursor[d], 1);
        src_sorted[pos] = s;
    }
}

// ---------------- W pack: fp32 [128][128] -> MFMA-frag-ordered bf16 hi/lo ----------------

__global__ void pack_w(const float* __restrict__ W, short* __restrict__ Whi,
                       short* __restrict__ Wlo, int slot) {
    int lane = threadIdx.x;            // 64
    int ctkk = blockIdx.x;             // 32: ct*4+kk
    int ct = ctkk >> 2, kk = ctkk & 3;
    int col = ct * 16 + (lane & 15);
    int k0 = kk * 32 + (lane >> 4) * 8;
    short8v h, l;
    #pragma unroll
    for (int j = 0; j < 8; j++) {
        float v = W[(size_t)(k0 + j) * FD + col];
        unsigned short hh = f32_to_bf16_rne(v);
        float rem = v - bf16_to_f32(hh);
        h[j] = (short)hh;
        l[j] = (short)f32_to_bf16_rne(rem);
    }
    size_t o = ((size_t)slot * 32 + ctkk) * 512 + (size_t)lane * 8;
    *(short8v*)(Whi + o) = h;
    *(short8v*)(Wlo + o) = l;
}

// ---------------- fused 4-projection GEMM via bf16 MFMA, fp32-split 3-pass ----------------

__global__ __launch_bounds__(256) void proj_gemm_mfma(
    const float* __restrict__ X,
    const short* __restrict__ Whi, const short* __restrict__ Wlo,   // layer base (4 slots)
    const float* __restrict__ b0, const float* __restrict__ b1,
    const float* __restrict__ b2, const float* __restrict__ b3,
    float* __restrict__ Y0, float* __restrict__ Y1,
    float* __restrict__ Y2, float* __restrict__ Y3)
{
    int wid = threadIdx.x >> 6, lane = threadIdx.x & 63;
    int rowbase = blockIdx.x * 64 + wid * 16;
    int r = lane & 15, q = lane >> 4;
    int row = rowbase + r;

    short8v xh[4], xl[4];
    if (row < NNODES) {
        const float* xp = X + (size_t)row * FD + q * 8;
        #pragma unroll
        for (int kk = 0; kk < 4; kk++) {
            float4 v0 = *(const float4*)(xp + kk * 32);
            float4 v1 = *(const float4*)(xp + kk * 32 + 4);
            float vv[8] = {v0.x, v0.y, v0.z, v0.w, v1.x, v1.y, v1.z, v1.w};
            #pragma unroll
            for (int j = 0; j < 8; j++) {
                unsigned short h = f32_to_bf16_rne(vv[j]);
                float rem = vv[j] - bf16_to_f32(h);
                xh[kk][j] = (short)h;
                xl[kk][j] = (short)f32_to_bf16_rne(rem);
            }
        }
    } else {
        short8v z = {0, 0, 0, 0, 0, 0, 0, 0};
        #pragma unroll
        for (int kk = 0; kk < 4; kk++) { xh[kk] = z; xl[kk] = z; }
    }

    #pragma unroll
    for (int pt = 0; pt < 4; pt++) {
        const float* bias = (pt == 0) ? b0 : (pt == 1) ? b1 : (pt == 2) ? b2 : b3;
        float*       Y    = (pt == 0) ? Y0 : (pt == 1) ? Y1 : (pt == 2) ? Y2 : Y3;
        #pragma unroll
        for (int ct = 0; ct < 8; ct++) {
            const short* wp = Whi + ((size_t)(pt * 8 + ct) * 4) * 512 + (size_t)lane * 8;
            const short* lp = Wlo + ((size_t)(pt * 8 + ct) * 4) * 512 + (size_t)lane * 8;
            f32x4 acc = {0.f, 0.f, 0.f, 0.f};
            #pragma unroll
            for (int kk = 0; kk < 4; kk++) {
                short8v bh = *(const short8v*)(wp + kk * 512);
                short8v bl = *(const short8v*)(lp + kk * 512);
                acc = __builtin_amdgcn_mfma_f32_16x16x32_bf16(xh[kk], bh, acc, 0, 0, 0);
                acc = __builtin_amdgcn_mfma_f32_16x16x32_bf16(xl[kk], bh, acc, 0, 0, 0);
                acc = __builtin_amdgcn_mfma_f32_16x16x32_bf16(xh[kk], bl, acc, 0, 0, 0);
            }
            float bb = bias[ct * 16 + r];
            #pragma unroll
            for (int j = 0; j < 4; j++) {
                int ro = rowbase + q * 4 + j;          // D: col=lane&15, row=(lane>>4)*4+j
                if (ro < NNODES)
                    Y[(size_t)ro * FD + ct * 16 + r] = acc[j] + bb;
            }
        }
    }
}

// ---------------- per-node online-softmax aggregation (one wave per dst node) ----------------
// Software-pipelined depth 4: all 8 row loads of a 4-edge chunk issue before the
// dependent shuffle/exp chain. Tail edges clamp to chunk-base index (L1-hot dup row,
// result unused); tail branches are wave-uniform.

__global__ __launch_bounds__(256) void agg_kernel(
    const float* __restrict__ Q, const float* __restrict__ K, const float* __restrict__ V,
    const float* __restrict__ SKIP, float* __restrict__ OUT,
    const int* __restrict__ row_ptr, const int* __restrict__ src_sorted, int apply_elu)
{
    int wid  = threadIdx.x >> 6;
    int lane = threadIdx.x & 63;
    int node = blockIdx.x * 4 + wid;
    if (node >= NNODES) return;
    size_t rb = (size_t)node * FD;
    float2 q = *(const float2*)(Q + rb + 2 * lane);
    q.x *= 0.125f; q.y *= 0.125f;          // 1/sqrt(64)
    float m = -INFINITY, s = 0.f;
    float accx = 0.f, accy = 0.f;
    int e0 = row_ptr[node], e1 = row_ptr[node + 1];

    const float2* K2 = (const float2*)K;
    const float2* V2 = (const float2*)V;

#define EDGE_UPD(KK, VV)                                     \
    {                                                        \
        float p = q.x * (KK).x + q.y * (KK).y;               \
        p += __shfl_xor(p, 1, 64);                           \
        p += __shfl_xor(p, 2, 64);                           \
        p += __shfl_xor(p, 4, 64);                           \
        p += __shfl_xor(p, 8, 64);                           \
        p += __shfl_xor(p, 16, 64);                          \
        float mn   = fmaxf(m, p);                            \
        float corr = __expf(m - mn);                         \
        float w    = __expf(p - mn);                         \
        s    = s * corr + w;                                 \
        accx = accx * corr + w * (VV).x;                     \
        accy = accy * corr + w * (VV).y;                     \
        m = mn;                                              \
    }

    for (int base = e0; base < e1; base += 4) {
        int nrem = e1 - base;                 // >= 1
        int j0 = src_sorted[base];
        int j1 = src_sorted[nrem > 1 ? base + 1 : base];
        int j2 = src_sorted[nrem > 2 ? base + 2 : base];
        int j3 = src_sorted[nrem > 3 ? base + 3 : base];
        float2 k0 = K2[(size_t)j0 * 64 + lane], v0 = V2[(size_t)j0 * 64 + lane];
        float2 k1 = K2[(size_t)j1 * 64 + lane], v1 = V2[(size_t)j1 * 64 + lane];
        float2 k2 = K2[(size_t)j2 * 64 + lane], v2 = V2[(size_t)j2 * 64 + lane];
        float2 k3 = K2[(size_t)j3 * 64 + lane], v3 = V2[(size_t)j3 * 64 + lane];
        EDGE_UPD(k0, v0)
        if (nrem > 1) EDGE_UPD(k1, v1)
        if (nrem > 2) EDGE_UPD(k2, v2)
        if (nrem > 3) EDGE_UPD(k3, v3)
    }
#undef EDGE_UPD

    float r = 1.f / (s + 1e-16f);
    float2 sk = *(const float2*)(SKIP + rb + 2 * lane);
    float ox = accx * r + sk.x;
    float oy = accy * r + sk.y;
    if (apply_elu) {
        ox = (ox > 0.f) ? ox : (__expf(ox) - 1.f);
        oy = (oy > 0.f) ? oy : (__expf(oy) - 1.f);
    }
    *(float2*)(OUT + rb + 2 * lane) = make_float2(ox, oy);
}

// ---------------- final classifier: out = H @ Wlin + blin  ([N,128] @ [128,40]) ----------------

__global__ void final_lin(const float* __restrict__ H, const float* __restrict__ Wl,
                          const float* __restrict__ bl, float* __restrict__ out)
{
    __shared__ float ws[FD * NCLS];    // 20 KB
    __shared__ float xs[8][FD + 1];
    int tx = threadIdx.x;              // 0..39 (col)
    int ty = threadIdx.y;              // 0..7  (row)
    int t = ty * NCLS + tx;
    for (int i = t; i < FD * NCLS; i += 320) ws[i] = Wl[i];
    int row = blockIdx.x * 8;
    for (int i = t; i < 8 * FD; i += 320) {
        int r = i >> 7, c = i & 127;
        xs[r][c] = (row + r < NNODES) ? H[(size_t)(row + r) * FD + c] : 0.f;
    }
    __syncthreads();
    float acc = bl[tx];
    #pragma unroll
    for (int k = 0; k < FD; k++) acc += xs[ty][k] * ws[k * NCLS + tx];
    if (row + ty < NNODES) out[(size_t)(row + ty) * NCLS + tx] = acc;
}

// ---------------- launch ----------------

extern "C" void kernel_launch(void* const* d_in, const int* in_sizes, int n_in,
                              void* d_out, int out_size, void* d_ws, size_t ws_size,
                              hipStream_t stream) {
    const float* x  = (const float*)d_in[0];
    const void*  ei = d_in[1];
    const float* Wq1 = (const float*)d_in[2],  *bq1 = (const float*)d_in[3];
    const float* Wk1 = (const float*)d_in[4],  *bk1 = (const float*)d_in[5];
    const float* Wv1 = (const float*)d_in[6],  *bv1 = (const float*)d_in[7];
    const float* Ws1 = (const float*)d_in[8],  *bs1 = (const float*)d_in[9];
    const float* Wq2 = (const float*)d_in[10], *bq2 = (const float*)d_in[11];
    const float* Wk2 = (const float*)d_in[12], *bk2 = (const float*)d_in[13];
    const float* Wv2 = (const float*)d_in[14], *bv2 = (const float*)d_in[15];
    const float* Ws2 = (const float*)d_in[16], *bs2 = (const float*)d_in[17];
    const float* Wlin = (const float*)d_in[18], *blin = (const float*)d_in[19];
    float* out = (float*)d_out;

    const size_t BUFE = (size_t)NNODES * FD;
    float* Bb = (float*)d_ws;
    float* Cb = Bb + BUFE;
    float* Db = Cb + BUFE;
    float* Eb = Db + BUFE;
    float* Fb = Eb + BUFE;
    int* row_ptr    = (int*)(Fb + BUFE);            // N+1
    int* cursor     = row_ptr + (NNODES + 1);       // N
    int* src_sorted = cursor + NNODES;              // E
    int* flag_is32  = src_sorted + NEDGES;          // 1
    uintptr_t pal = ((uintptr_t)(flag_is32 + 1) + 15) & ~(uintptr_t)15;
    short* Whi = (short*)pal;                       // 8 slots x 16384 bf16 = 256 KB
    short* Wlo = Whi + 8 * 16384;

    // ---- weight packing (tiny) ----
    const float* Ws[8] = {Wq1, Wk1, Wv1, Ws1, Wq2, Wk2, Wv2, Ws2};
    for (int s = 0; s < 8; s++)
        pack_w<<<32, 64, 0, stream>>>(Ws[s], Whi, Wlo, s);

    // ---- dtype detect + CSR build ----
    hipMemsetAsync(row_ptr, 0, (NNODES + 1) * sizeof(int), stream);
    hipMemsetAsync(flag_is32, 0, sizeof(int), stream);
    detect_kernel<<<16, 256, 0, stream>>>((const long long*)ei, flag_is32);
    hist_kernel<<<(NEDGES + 255) / 256, 256, 0, stream>>>(ei, flag_is32, row_ptr);
    scan_kernel<<<1, 1024, 0, stream>>>(row_ptr, cursor);
    fill_kernel<<<(NEDGES + 255) / 256, 256, 0, stream>>>(ei, flag_is32, cursor, src_sorted);

    int pgrid = (NNODES + 63) / 64;

    // ---- layer 1 ----
    proj_gemm_mfma<<<pgrid, 256, 0, stream>>>(x, Whi, Wlo,
        bq1, bk1, bv1, bs1, Bb, Cb, Db, Eb);
    agg_kernel<<<(NNODES + 3) / 4, 256, 0, stream>>>(Bb, Cb, Db, Eb, Bb,
        row_ptr, src_sorted, 1);

    // ---- layer 2 ----
    proj_gemm_mfma<<<pgrid, 256, 0, stream>>>(Bb, Whi + 4 * 16384, Wlo + 4 * 16384,
        bq2, bk2, bv2, bs2, Cb, Db, Eb, Fb);
    agg_kernel<<<(NNODES + 3) / 4, 256, 0, stream>>>(Cb, Db, Eb, Fb, Cb,
        row_ptr, src_sorted, 0);

    // ---- classifier ----
    final_lin<<<(NNODES + 7) / 8, dim3(NCLS, 8), 0, stream>>>(Cb, Wlin, blin, out);
}

// Round 7
// 946.960 us; speedup vs baseline: 1.9275x; 1.2589x over previous
//
#include <hip/hip_runtime.h>
#include <math.h>

#define NNODES 100000
#define NEDGES 1600000
#define FD 128
#define NCLS 40
#define NB_SCAN ((NNODES + 1023) / 1024)   // 98

typedef __attribute__((ext_vector_type(8))) short short8v;   // 8 x bf16 (4 VGPR)
typedef __attribute__((ext_vector_type(4))) float f32x4;

__device__ __forceinline__ unsigned short f32_to_bf16_rne(float f) {
    unsigned int u = __float_as_uint(f);
    unsigned int r = u + 0x7fff + ((u >> 16) & 1);
    return (unsigned short)(r >> 16);
}
__device__ __forceinline__ float bf16_to_f32(unsigned short h) {
    return __uint_as_float(((unsigned int)h) << 16);
}

// ---------------- edge_index dtype detection (int64 vs harness-narrowed int32) -------------

__global__ void detect_kernel(const long long* __restrict__ ei, int* __restrict__ flag_is32) {
    int t = blockIdx.x * blockDim.x + threadIdx.x;      // 4096 threads
    size_t idx = (size_t)t * (NEDGES / 4096);           // < NEDGES
    long long v = ei[idx];
    if (v < 0 || v >= NNODES) atomicOr(flag_is32, 1);
}

__device__ __forceinline__ void load_edge(const void* eiv, int is32, int e, int& s, int& d) {
    if (is32) {
        const int* p = (const int*)eiv;
        s = p[e]; d = p[NEDGES + e];
    } else {
        const long long* p = (const long long*)eiv;
        s = (int)p[e]; d = (int)p[NEDGES + e];
    }
}

// ---------------- CSR build (dst-sorted adjacency), built once per call ----------------

__global__ void hist_kernel(const void* __restrict__ eiv, const int* __restrict__ flag_is32,
                            int* __restrict__ row_ptr) {
    int is32 = *flag_is32;
    int e = blockIdx.x * blockDim.x + threadIdx.x;
    if (e < NEDGES) {
        int s, d;
        load_edge(eiv, is32, e, s, d);
        atomicAdd(&row_ptr[d + 1], 1);
    }
}

// 98 blocks: local inclusive scan of 1024 counts; row_ptr[1+i] = local incl,
// cursor[i] = local excl, blk_tot[b] = block sum.
__global__ __launch_bounds__(1024) void scan_blk(int* __restrict__ row_ptr,
                                                 int* __restrict__ cursor,
                                                 int* __restrict__ blk_tot) {
    __shared__ int wtot[16];
    __shared__ int woff[16];
    int t = threadIdx.x, lane = t & 63, wid = t >> 6;
    int i = blockIdx.x * 1024 + t;
    int c = (i < NNODES) ? row_ptr[1 + i] : 0;
    int x = c;
    #pragma unroll
    for (int off = 1; off < 64; off <<= 1) {
        int y = __shfl_up(x, off, 64);
        if (lane >= off) x += y;
    }
    if (lane == 63) wtot[wid] = x;
    __syncthreads();
    if (t < 16) {
        int v = wtot[t];
        #pragma unroll
        for (int off = 1; off < 16; off <<= 1) {
            int y = __shfl_up(v, off, 64);
            if (t >= off) v += y;
        }
        woff[t] = v;
    }
    __syncthreads();
    int excl = (wid == 0) ? 0 : woff[wid - 1];
    int incl = x + excl;
    if (i < NNODES) {
        row_ptr[1 + i] = incl;
        cursor[i]      = incl - c;
    }
    if (t == 0) blk_tot[blockIdx.x] = woff[15];
}

// 1 block x 128: exclusive scan of the 98 block totals.
__global__ void scan_tops(const int* __restrict__ blk_tot, int* __restrict__ blk_off) {
    __shared__ int s[128];
    int t = threadIdx.x;
    int c0 = (t < NB_SCAN) ? blk_tot[t] : 0;
    s[t] = c0;
    __syncthreads();
    for (int d = 1; d < 128; d <<= 1) {
        int v = (t >= d) ? s[t - d] : 0;
        __syncthreads();
        s[t] += v;
        __syncthreads();
    }
    if (t < NB_SCAN) blk_off[t] = s[t] - c0;
}

// 98 blocks: add block offsets.
__global__ __launch_bounds__(1024) void scan_add(int* __restrict__ row_ptr,
                                                 int* __restrict__ cursor,
                                                 const int* __restrict__ blk_off) {
    int i = blockIdx.x * 1024 + threadIdx.x;
    if (i < NNODES) {
        int o = blk_off[blockIdx.x];
        row_ptr[1 + i] += o;
        cursor[i]      += o;
    }
}

__global__ void fill_kernel(const void* __restrict__ eiv, const int* __restrict__ flag_is32,
                            int* __restrict__ cursor, int* __restrict__ src_sorted) {
    int is32 = *flag_is32;
    int e = blockIdx.x * blockDim.x + threadIdx.x;
    if (e < NEDGES) {
        int s, d;
        load_edge(eiv, is32, e, s, d);
        int pos = atomicAdd(&cursor[d], 1);
        src_sorted[pos] = s;
    }
}

// ---------------- W pack: fp32 [128][128] -> MFMA-frag-ordered bf16 hi/lo ----------------

__global__ void pack_w(const float* __restrict__ W, short* __restrict__ Whi,
                       short* __restrict__ Wlo, int slot) {
    int lane = threadIdx.x;            // 64
    int ctkk = blockIdx.x;             // 32: ct*4+kk
    int ct = ctkk >> 2, kk = ctkk & 3;
    int col = ct * 16 + (lane & 15);
    int k0 = kk * 32 + (lane >> 4) * 8;
    short8v h, l;
    #pragma unroll
    for (int j = 0; j < 8; j++) {
        float v = W[(size_t)(k0 + j) * FD + col];
        unsigned short hh = f32_to_bf16_rne(v);
        float rem = v - bf16_to_f32(hh);
        h[j] = (short)hh;
        l[j] = (short)f32_to_bf16_rne(rem);
    }
    size_t o = ((size_t)slot * 32 + ctkk) * 512 + (size_t)lane * 8;
    *(short8v*)(Whi + o) = h;
    *(short8v*)(Wlo + o) = l;
}

// ---------------- fused 4-projection GEMM via bf16 MFMA, fp32-split 3-pass ----------------
// Outputs: pt0 -> Q (fp32), pt1 -> K (bf16, KV even slots), pt2 -> V (bf16, KV odd slots),
// pt3 -> SKIP (fp32). KV layout: kv[row][2e] = k_e, kv[row][2e+1] = v_e (interleaved).

__global__ __launch_bounds__(256) void proj_gemm_mfma(
    const float* __restrict__ X,
    const short* __restrict__ Whi, const short* __restrict__ Wlo,   // layer base (4 slots)
    const float* __restrict__ b0, const float* __restrict__ b1,
    const float* __restrict__ b2, const float* __restrict__ b3,
    float* __restrict__ Q, unsigned short* __restrict__ KV, float* __restrict__ SKIP)
{
    int wid = threadIdx.x >> 6, lane = threadIdx.x & 63;
    int rowbase = blockIdx.x * 64 + wid * 16;
    int r = lane & 15, q = lane >> 4;
    int row = rowbase + r;

    short8v xh[4], xl[4];
    if (row < NNODES) {
        const float* xp = X + (size_t)row * FD + q * 8;
        #pragma unroll
        for (int kk = 0; kk < 4; kk++) {
            float4 v0 = *(const float4*)(xp + kk * 32);
            float4 v1 = *(const float4*)(xp + kk * 32 + 4);
            float vv[8] = {v0.x, v0.y, v0.z, v0.w, v1.x, v1.y, v1.z, v1.w};
            #pragma unroll
            for (int j = 0; j < 8; j++) {
                unsigned short h = f32_to_bf16_rne(vv[j]);
                float rem = vv[j] - bf16_to_f32(h);
                xh[kk][j] = (short)h;
                xl[kk][j] = (short)f32_to_bf16_rne(rem);
            }
        }
    } else {
        short8v z = {0, 0, 0, 0, 0, 0, 0, 0};
        #pragma unroll
        for (int kk = 0; kk < 4; kk++) { xh[kk] = z; xl[kk] = z; }
    }

    #pragma unroll
    for (int pt = 0; pt < 4; pt++) {
        const float* bias = (pt == 0) ? b0 : (pt == 1) ? b1 : (pt == 2) ? b2 : b3;
        #pragma unroll
        for (int ct = 0; ct < 8; ct++) {
            const short* wp = Whi + ((size_t)(pt * 8 + ct) * 4) * 512 + (size_t)lane * 8;
            const short* lp = Wlo + ((size_t)(pt * 8 + ct) * 4) * 512 + (size_t)lane * 8;
            f32x4 acc = {0.f, 0.f, 0.f, 0.f};
            #pragma unroll
            for (int kk = 0; kk < 4; kk++) {
                short8v bh = *(const short8v*)(wp + kk * 512);
                short8v bl = *(const short8v*)(lp + kk * 512);
                acc = __builtin_amdgcn_mfma_f32_16x16x32_bf16(xh[kk], bh, acc, 0, 0, 0);
                acc = __builtin_amdgcn_mfma_f32_16x16x32_bf16(xl[kk], bh, acc, 0, 0, 0);
                acc = __builtin_amdgcn_mfma_f32_16x16x32_bf16(xh[kk], bl, acc, 0, 0, 0);
            }
            float bb = bias[ct * 16 + r];
            int e = ct * 16 + r;
            #pragma unroll
            for (int j = 0; j < 4; j++) {
                int ro = rowbase + q * 4 + j;          // D: col=lane&15, row=(lane>>4)*4+j
                if (ro < NNODES) {
                    float val = acc[j] + bb;
                    if (pt == 0)      Q[(size_t)ro * FD + e] = val;
                    else if (pt == 1) KV[(size_t)ro * 256 + 2 * e]     = f32_to_bf16_rne(val);
                    else if (pt == 2) KV[(size_t)ro * 256 + 2 * e + 1] = f32_to_bf16_rne(val);
                    else              SKIP[(size_t)ro * FD + e] = val;
                }
            }
        }
    }
}

// ---------------- per-node online-softmax aggregation (one wave per dst node) ----------------
// bf16 interleaved KV: lane l reads ONE dwordx2 (8B) per edge = (k_{2l},v_{2l},k_{2l+1},v_{2l+1}).
// Depth-4 pipeline; tail edges clamp to chunk base (wave-uniform branches, results unused).

__global__ __launch_bounds__(256) void agg_kernel(
    const float* __restrict__ Q, const unsigned short* __restrict__ KV,
    const float* __restrict__ SKIP, float* __restrict__ OUT,
    const int* __restrict__ row_ptr, const int* __restrict__ src_sorted, int apply_elu)
{
    int wid  = threadIdx.x >> 6;
    int lane = threadIdx.x & 63;
    int node = blockIdx.x * 4 + wid;
    if (node >= NNODES) return;
    size_t rb = (size_t)node * FD;
    float2 q = *(const float2*)(Q + rb + 2 * lane);
    q.x *= 0.125f; q.y *= 0.125f;          // 1/sqrt(64)
    float m = -INFINITY, s = 0.f;
    float accx = 0.f, accy = 0.f;
    int e0 = row_ptr[node], e1 = row_ptr[node + 1];

#define EDGE_UPD(W)                                          \
    {                                                        \
        float kx = bf16_to_f32((W).x & 0xffffu);             \
        float vx = bf16_to_f32((W).x >> 16);                 \
        float ky = bf16_to_f32((W).y & 0xffffu);             \
        float vy = bf16_to_f32((W).y >> 16);                 \
        float p = q.x * kx + q.y * ky;                       \
        p += __shfl_xor(p, 1, 64);                           \
        p += __shfl_xor(p, 2, 64);                           \
        p += __shfl_xor(p, 4, 64);                           \
        p += __shfl_xor(p, 8, 64);                           \
        p += __shfl_xor(p, 16, 64);                          \
        float mn   = fmaxf(m, p);                            \
        float corr = __expf(m - mn);                         \
        float w    = __expf(p - mn);                         \
        s    = s * corr + w;                                 \
        accx = accx * corr + w * vx;                         \
        accy = accy * corr + w * vy;                         \
        m = mn;                                              \
    }

    for (int base = e0; base < e1; base += 4) {
        int nrem = e1 - base;                 // >= 1
        int j0 = src_sorted[base];
        int j1 = src_sorted[nrem > 1 ? base + 1 : base];
        int j2 = src_sorted[nrem > 2 ? base + 2 : base];
        int j3 = src_sorted[nrem > 3 ? base + 3 : base];
        uint2 w0 = *(const uint2*)((const unsigned int*)(KV + (size_t)j0 * 256) + 2 * lane);
        uint2 w1 = *(const uint2*)((const unsigned int*)(KV + (size_t)j1 * 256) + 2 * lane);
        uint2 w2 = *(const uint2*)((const unsigned int*)(KV + (size_t)j2 * 256) + 2 * lane);
        uint2 w3 = *(const uint2*)((const unsigned int*)(KV + (size_t)j3 * 256) + 2 * lane);
        EDGE_UPD(w0)
        if (nrem > 1) EDGE_UPD(w1)
        if (nrem > 2) EDGE_UPD(w2)
        if (nrem > 3) EDGE_UPD(w3)
    }
#undef EDGE_UPD

    float r = 1.f / (s + 1e-16f);
    float2 sk = *(const float2*)(SKIP + rb + 2 * lane);
    float ox = accx * r + sk.x;
    float oy = accy * r + sk.y;
    if (apply_elu) {
        ox = (ox > 0.f) ? ox : (__expf(ox) - 1.f);
        oy = (oy > 0.f) ? oy : (__expf(oy) - 1.f);
    }
    *(float2*)(OUT + rb + 2 * lane) = make_float2(ox, oy);
}

// ---------------- final classifier: out = H @ Wlin + blin  ([N,128] @ [128,40]) ----------------

__global__ void final_lin(const float* __restrict__ H, const float* __restrict__ Wl,
                          const float* __restrict__ bl, float* __restrict__ out)
{
    __shared__ float ws[FD * NCLS];    // 20 KB
    __shared__ float xs[8][FD + 1];
    int tx = threadIdx.x;              // 0..39 (col)
    int ty = threadIdx.y;              // 0..7  (row)
    int t = ty * NCLS + tx;
    for (int i = t; i < FD * NCLS; i += 320) ws[i] = Wl[i];
    int row = blockIdx.x * 8;
    for (int i = t; i < 8 * FD; i += 320) {
        int r = i >> 7, c = i & 127;
        xs[r][c] = (row + r < NNODES) ? H[(size_t)(row + r) * FD + c] : 0.f;
    }
    __syncthreads();
    float acc = bl[tx];
    #pragma unroll
    for (int k = 0; k < FD; k++) acc += xs[ty][k] * ws[k * NCLS + tx];
    if (row + ty < NNODES) out[(size_t)(row + ty) * NCLS + tx] = acc;
}

// ---------------- launch ----------------

extern "C" void kernel_launch(void* const* d_in, const int* in_sizes, int n_in,
                              void* d_out, int out_size, void* d_ws, size_t ws_size,
                              hipStream_t stream) {
    const float* x  = (const float*)d_in[0];
    const void*  ei = d_in[1];
    const float* Wq1 = (const float*)d_in[2],  *bq1 = (const float*)d_in[3];
    const float* Wk1 = (const float*)d_in[4],  *bk1 = (const float*)d_in[5];
    const float* Wv1 = (const float*)d_in[6],  *bv1 = (const float*)d_in[7];
    const float* Ws1 = (const float*)d_in[8],  *bs1 = (const float*)d_in[9];
    const float* Wq2 = (const float*)d_in[10], *bq2 = (const float*)d_in[11];
    const float* Wk2 = (const float*)d_in[12], *bk2 = (const float*)d_in[13];
    const float* Wv2 = (const float*)d_in[14], *bv2 = (const float*)d_in[15];
    const float* Ws2 = (const float*)d_in[16], *bs2 = (const float*)d_in[17];
    const float* Wlin = (const float*)d_in[18], *blin = (const float*)d_in[19];
    float* out = (float*)d_out;

    const size_t BUFE = (size_t)NNODES * FD;        // 12.8M floats
    float* Qb = (float*)d_ws;                       // Q / layer output (fp32)
    float* Cb = Qb + BUFE;                          // layer-2 Q / output (fp32)
    float* Sb = Cb + BUFE;                          // SKIP (fp32, reused per layer)
    unsigned short* KVb = (unsigned short*)(Sb + BUFE);   // N x 256 bf16 interleaved K/V
    int* row_ptr    = (int*)(KVb + (size_t)NNODES * 256); // N+1
    int* cursor     = row_ptr + (NNODES + 1);       // N
    int* src_sorted = cursor + NNODES;              // E
    int* flag_is32  = src_sorted + NEDGES;          // 1
    int* blk_tot    = flag_is32 + 1;                // NB_SCAN
    int* blk_off    = blk_tot + NB_SCAN;            // NB_SCAN
    uintptr_t pal = ((uintptr_t)(blk_off + NB_SCAN) + 15) & ~(uintptr_t)15;
    short* Whi = (short*)pal;                       // 8 slots x 16384 bf16 = 256 KB
    short* Wlo = Whi + 8 * 16384;

    // ---- weight packing (tiny) ----
    const float* Ws[8] = {Wq1, Wk1, Wv1, Ws1, Wq2, Wk2, Wv2, Ws2};
    for (int s = 0; s < 8; s++)
        pack_w<<<32, 64, 0, stream>>>(Ws[s], Whi, Wlo, s);

    // ---- dtype detect + CSR build ----
    hipMemsetAsync(row_ptr, 0, (NNODES + 1) * sizeof(int), stream);
    hipMemsetAsync(flag_is32, 0, sizeof(int), stream);
    detect_kernel<<<16, 256, 0, stream>>>((const long long*)ei, flag_is32);
    hist_kernel<<<(NEDGES + 255) / 256, 256, 0, stream>>>(ei, flag_is32, row_ptr);
    scan_blk<<<NB_SCAN, 1024, 0, stream>>>(row_ptr, cursor, blk_tot);
    scan_tops<<<1, 128, 0, stream>>>(blk_tot, blk_off);
    scan_add<<<NB_SCAN, 1024, 0, stream>>>(row_ptr, cursor, blk_off);
    fill_kernel<<<(NEDGES + 255) / 256, 256, 0, stream>>>(ei, flag_is32, cursor, src_sorted);

    int pgrid = (NNODES + 63) / 64;

    // ---- layer 1 ----
    proj_gemm_mfma<<<pgrid, 256, 0, stream>>>(x, Whi, Wlo,
        bq1, bk1, bv1, bs1, Qb, KVb, Sb);
    agg_kernel<<<(NNODES + 3) / 4, 256, 0, stream>>>(Qb, KVb, Sb, Qb,
        row_ptr, src_sorted, 1);

    // ---- layer 2 ----
    proj_gemm_mfma<<<pgrid, 256, 0, stream>>>(Qb, Whi + 4 * 16384, Wlo + 4 * 16384,
        bq2, bk2, bv2, bs2, Cb, KVb, Sb);
    agg_kernel<<<(NNODES + 3) / 4, 256, 0, stream>>>(Cb, KVb, Sb, Cb,
        row_ptr, src_sorted, 0);

    // ---- classifier ----
    final_lin<<<(NNODES + 7) / 8, dim3(NCLS, 8), 0, stream>>>(Cb, Wlin, blin, out);
}

// Round 10
// 906.730 us; speedup vs baseline: 2.0130x; 1.0444x over previous
//
#include <hip/hip_runtime.h>
#include <math.h>

#define NNODES 100000
#define NEDGES 1600000
#define FD 128
#define NCLS 40
#define NB_SCAN ((NNODES + 1023) / 1024)   // 98

typedef __attribute__((ext_vector_type(8))) short short8v;   // 8 x bf16 (4 VGPR)
typedef __attribute__((ext_vector_type(4))) float f32x4;

__device__ __forceinline__ unsigned short f32_to_bf16_rne(float f) {
    unsigned int u = __float_as_uint(f);
    unsigned int r = u + 0x7fff + ((u >> 16) & 1);
    return (unsigned short)(r >> 16);
}
__device__ __forceinline__ float bf16_to_f32(unsigned short h) {
    return __uint_as_float(((unsigned int)h) << 16);
}

// ---------------- edge_index dtype detection (int64 vs harness-narrowed int32) -------------

__global__ void detect_kernel(const long long* __restrict__ ei, int* __restrict__ flag_is32) {
    int t = blockIdx.x * blockDim.x + threadIdx.x;      // 4096 threads
    size_t idx = (size_t)t * (NEDGES / 4096);           // < NEDGES
    long long v = ei[idx];
    if (v < 0 || v >= NNODES) atomicOr(flag_is32, 1);
}

__device__ __forceinline__ void load_edge(const void* eiv, int is32, int e, int& s, int& d) {
    if (is32) {
        const int* p = (const int*)eiv;
        s = p[e]; d = p[NEDGES + e];
    } else {
        const long long* p = (const long long*)eiv;
        s = (int)p[e]; d = (int)p[NEDGES + e];
    }
}

// ---------------- CSR build (dst-sorted adjacency), built once per call ----------------

__global__ void hist_kernel(const void* __restrict__ eiv, const int* __restrict__ flag_is32,
                            int* __restrict__ row_ptr) {
    int is32 = *flag_is32;
    int e = blockIdx.x * blockDim.x + threadIdx.x;
    if (e < NEDGES) {
        int s, d;
        load_edge(eiv, is32, e, s, d);
        atomicAdd(&row_ptr[d + 1], 1);
    }
}

// 98 blocks: local inclusive scan of 1024 counts
__global__ __launch_bounds__(1024) void scan_blk(int* __restrict__ row_ptr,
                                                 int* __restrict__ cursor,
                                                 int* __restrict__ blk_tot) {
    __shared__ int wtot[16];
    __shared__ int woff[16];
    int t = threadIdx.x, lane = t & 63, wid = t >> 6;
    int i = blockIdx.x * 1024 + t;
    int c = (i < NNODES) ? row_ptr[1 + i] : 0;
    int x = c;
    #pragma unroll
    for (int off = 1; off < 64; off <<= 1) {
        int y = __shfl_up(x, off, 64);
        if (lane >= off) x += y;
    }
    if (lane == 63) wtot[wid] = x;
    __syncthreads();
    if (t < 16) {
        int v = wtot[t];
        #pragma unroll
        for (int off = 1; off < 16; off <<= 1) {
            int y = __shfl_up(v, off, 64);
            if (t >= off) v += y;
        }
        woff[t] = v;
    }
    __syncthreads();
    int excl = (wid == 0) ? 0 : woff[wid - 1];
    int incl = x + excl;
    if (i < NNODES) {
        row_ptr[1 + i] = incl;
        cursor[i]      = incl - c;
    }
    if (t == 0) blk_tot[blockIdx.x] = woff[15];
}

// 1 block x 128: exclusive scan of the 98 block totals.
__global__ void scan_tops(const int* __restrict__ blk_tot, int* __restrict__ blk_off) {
    __shared__ int s[128];
    int t = threadIdx.x;
    int c0 = (t < NB_SCAN) ? blk_tot[t] : 0;
    s[t] = c0;
    __syncthreads();
    for (int d = 1; d < 128; d <<= 1) {
        int v = (t >= d) ? s[t - d] : 0;
        __syncthreads();
        s[t] += v;
        __syncthreads();
    }
    if (t < NB_SCAN) blk_off[t] = s[t] - c0;
}

// 98 blocks: add block offsets.
__global__ __launch_bounds__(1024) void scan_add(int* __restrict__ row_ptr,
                                                 int* __restrict__ cursor,
                                                 const int* __restrict__ blk_off) {
    int i = blockIdx.x * 1024 + threadIdx.x;
    if (i < NNODES) {
        int o = blk_off[blockIdx.x];
        row_ptr[1 + i] += o;
        cursor[i]      += o;
    }
}

__global__ void fill_kernel(const void* __restrict__ eiv, const int* __restrict__ flag_is32,
                            int* __restrict__ cursor, int* __restrict__ src_sorted) {
    int is32 = *flag_is32;
    int e = blockIdx.x * blockDim.x + threadIdx.x;
    if (e < NEDGES) {
        int s, d;
        load_edge(eiv, is32, e, s, d);
        int pos = atomicAdd(&cursor[d], 1);
        src_sorted[pos] = s;
    }
}

// ---------------- W pack: fp32 [128][128] -> MFMA-frag-ordered bf16 hi/lo ----------------

__global__ void pack_w(const float* __restrict__ W, short* __restrict__ Whi,
                       short* __restrict__ Wlo, int slot) {
    int lane = threadIdx.x;            // 64
    int ctkk = blockIdx.x;             // 32: ct*4+kk
    int ct = ctkk >> 2, kk = ctkk & 3;
    int col = ct * 16 + (lane & 15);
    int k0 = kk * 32 + (lane >> 4) * 8;
    short8v h, l;
    #pragma unroll
    for (int j = 0; j < 8; j++) {
        float v = W[(size_t)(k0 + j) * FD + col];
        unsigned short hh = f32_to_bf16_rne(v);
        float rem = v - bf16_to_f32(hh);
        h[j] = (short)hh;
        l[j] = (short)f32_to_bf16_rne(rem);
    }
    size_t o = ((size_t)slot * 32 + ctkk) * 512 + (size_t)lane * 8;
    *(short8v*)(Whi + o) = h;
    *(short8v*)(Wlo + o) = l;
}

// ---------------- fused 4-projection GEMM via bf16 MFMA, fp32-split 3-pass ----------------
// Outputs: pt0 -> Q (fp32), pt1 -> K (bf16, KV even slots), pt2 -> V (bf16, KV odd slots),
// pt3 -> SKIP (fp32). KV layout: kv[row][2e] = k_e, kv[row][2e+1] = v_e (interleaved).

__global__ __launch_bounds__(256) void proj_gemm_mfma(
    const float* __restrict__ X,
    const short* __restrict__ Whi, const short* __restrict__ Wlo,   // layer base (4 slots)
    const float* __restrict__ b0, const float* __restrict__ b1,
    const float* __restrict__ b2, const float* __restrict__ b3,
    float* __restrict__ Q, unsigned short* __restrict__ KV, float* __restrict__ SKIP)
{
    int wid = threadIdx.x >> 6, lane = threadIdx.x & 63;
    int rowbase = blockIdx.x * 64 + wid * 16;
    int r = lane & 15, q = lane >> 4;
    int row = rowbase + r;

    short8v xh[4], xl[4];
    if (row < NNODES) {
        const float* xp = X + (size_t)row * FD + q * 8;
        #pragma unroll
        for (int kk = 0; kk < 4; kk++) {
            float4 v0 = *(const float4*)(xp + kk * 32);
            float4 v1 = *(const float4*)(xp + kk * 32 + 4);
            float vv[8] = {v0.x, v0.y, v0.z, v0.w, v1.x, v1.y, v1.z, v1.w};
            #pragma unroll
            for (int j = 0; j < 8; j++) {
                unsigned short h = f32_to_bf16_rne(vv[j]);
                float rem = vv[j] - bf16_to_f32(h);
                xh[kk][j] = (short)h;
                xl[kk][j] = (short)f32_to_bf16_rne(rem);
            }
        }
    } else {
        short8v z = {0, 0, 0, 0, 0, 0, 0, 0};
        #pragma unroll
        for (int kk = 0; kk < 4; kk++) { xh[kk] = z; xl[kk] = z; }
    }

    #pragma unroll
    for (int pt = 0; pt < 4; pt++) {
        const float* bias = (pt == 0) ? b0 : (pt == 1) ? b1 : (pt == 2) ? b2 : b3;
        #pragma unroll
        for (int ct = 0; ct < 8; ct++) {
            const short* wp = Whi + ((size_t)(pt * 8 + ct) * 4) * 512 + (size_t)lane * 8;
            const short* lp = Wlo + ((size_t)(pt * 8 + ct) * 4) * 512 + (size_t)lane * 8;
            f32x4 acc = {0.f, 0.f, 0.f, 0.f};
            #pragma unroll
            for (int kk = 0; kk < 4; kk++) {
                short8v bh = *(const short8v*)(wp + kk * 512);
                short8v bl = *(const short8v*)(lp + kk * 512);
                acc = __builtin_amdgcn_mfma_f32_16x16x32_bf16(xh[kk], bh, acc, 0, 0, 0);
                acc = __builtin_amdgcn_mfma_f32_16x16x32_bf16(xl[kk], bh, acc, 0, 0, 0);
                acc = __builtin_amdgcn_mfma_f32_16x16x32_bf16(xh[kk], bl, acc, 0, 0, 0);
            }
            float bb = bias[ct * 16 + r];
            int e = ct * 16 + r;
            #pragma unroll
            for (int j = 0; j < 4; j++) {
                int ro = rowbase + q * 4 + j;          // D: col=lane&15, row=(lane>>4)*4+j
                if (ro < NNODES) {
                    float val = acc[j] + bb;
                    if (pt == 0)      Q[(size_t)ro * FD + e] = val;
                    else if (pt == 1) KV[(size_t)ro * 256 + 2 * e]     = f32_to_bf16_rne(val);
                    else if (pt == 2) KV[(size_t)ro * 256 + 2 * e + 1] = f32_to_bf16_rne(val);
                    else              SKIP[(size_t)ro * FD + e] = val;
                }
            }
        }
    }
}

// ---------------- per-node softmax aggregation: 2 edges/wave, 4 channels/lane ----------------
// half = lane>>5 picks the edge of a pair; sub = lane&31 owns channels 4*sub..4*sub+3
// (one dwordx4 = 4 interleaved k,v pairs). Per-head score reduce = 4 shuffles over the
// 16-lane group. No online max: w = exp(alpha) in fp32 (cancels in the ratio; overflow
// needs alpha>88, unreachable). Halves combine once per node via xor-32 shuffle-add.

__global__ __launch_bounds__(256) void agg_kernel(
    const float* __restrict__ Q, const unsigned short* __restrict__ KV,
    const float* __restrict__ SKIP, float* __restrict__ OUT,
    const int* __restrict__ row_ptr, const int* __restrict__ src_sorted, int apply_elu)
{
    int wid  = threadIdx.x >> 6;
    int lane = threadIdx.x & 63;
    int half = lane >> 5;
    int sub  = lane & 31;
    int node = blockIdx.x * 4 + wid;
    if (node >= NNODES) return;
    size_t rb = (size_t)node * FD;

    float4 q4 = *(const float4*)(Q + rb + sub * 4);
    q4.x *= 0.125f; q4.y *= 0.125f; q4.z *= 0.125f; q4.w *= 0.125f;   // 1/sqrt(64)

    float s = 0.f;
    float4 acc = make_float4(0.f, 0.f, 0.f, 0.f);
    int e0 = row_ptr[node], e1 = row_ptr[node + 1];
    const uint4* KV4 = (const uint4*)KV;    // 8 shorts per uint4

#define PAIR_UPD(EID)                                                          \
    {                                                                          \
        int eid = (EID);                                                       \
        int valid = eid < e1;                                                  \
        int j = src_sorted[valid ? eid : e1 - 1];                              \
        uint4 wv = KV4[(size_t)j * 32 + sub];                                  \
        float kx = __uint_as_float(wv.x << 16);                                \
        float vx = __uint_as_float(wv.x & 0xffff0000u);                        \
        float ky = __uint_as_float(wv.y << 16);                                \
        float vy = __uint_as_float(wv.y & 0xffff0000u);                        \
        float kz = __uint_as_float(wv.z << 16);                                \
        float vz = __uint_as_float(wv.z & 0xffff0000u);                        \
        float kw = __uint_as_float(wv.w << 16);                                \
        float vw = __uint_as_float(wv.w & 0xffff0000u);                        \
        float p = q4.x * kx + q4.y * ky + q4.z * kz + q4.w * kw;               \
        p += __shfl_xor(p, 1, 64);                                             \
        p += __shfl_xor(p, 2, 64);                                             \
        p += __shfl_xor(p, 4, 64);                                             \
        p += __shfl_xor(p, 8, 64);         /* per-16-lane group = head sum */  \
        float w = valid ? __expf(p) : 0.f;                                     \
        s += w;                                                                \
        acc.x += w * vx; acc.y += w * vy;                                      \
        acc.z += w * vz; acc.w += w * vw;                                      \
    }

    for (int base = e0; base < e1; base += 4) {
        PAIR_UPD(base + half)
        PAIR_UPD(base + 2 + half)
    }
#undef PAIR_UPD

    // combine the two half-streams
    s += __shfl_xor(s, 32, 64);
    acc.x += __shfl_xor(acc.x, 32, 64);
    acc.y += __shfl_xor(acc.y, 32, 64);
    acc.z += __shfl_xor(acc.z, 32, 64);
    acc.w += __shfl_xor(acc.w, 32, 64);

    if (half == 0) {
        float r = 1.f / (s + 1e-16f);
        float4 sk = *(const float4*)(SKIP + rb + sub * 4);
        float ox = acc.x * r + sk.x;
        float oy = acc.y * r + sk.y;
        float oz = acc.z * r + sk.z;
        float ow = acc.w * r + sk.w;
        if (apply_elu) {
            ox = (ox > 0.f) ? ox : (__expf(ox) - 1.f);
            oy = (oy > 0.f) ? oy : (__expf(oy) - 1.f);
            oz = (oz > 0.f) ? oz : (__expf(oz) - 1.f);
            ow = (ow > 0.f) ? ow : (__expf(ow) - 1.f);
        }
        *(float4*)(OUT + rb + sub * 4) = make_float4(ox, oy, oz, ow);
    }
}

// ---------------- final classifier: out = H @ Wlin + blin  ([N,128] @ [128,40]) ----------------

__global__ void final_lin(const float* __restrict__ H, const float* __restrict__ Wl,
                          const float* __restrict__ bl, float* __restrict__ out)
{
    __shared__ float ws[FD * NCLS];    // 20 KB
    __shared__ float xs[8][FD + 1];
    int tx = threadIdx.x;              // 0..39 (col)
    int ty = threadIdx.y;              // 0..7  (row)
    int t = ty * NCLS + tx;
    for (int i = t; i < FD * NCLS; i += 320) ws[i] = Wl[i];
    int row = blockIdx.x * 8;
    for (int i = t; i < 8 * FD; i += 320) {
        int r = i >> 7, c = i & 127;
        xs[r][c] = (row + r < NNODES) ? H[(size_t)(row + r) * FD + c] : 0.f;
    }
    __syncthreads();
    float acc = bl[tx];
    #pragma unroll
    for (int k = 0; k < FD; k++) acc += xs[ty][k] * ws[k * NCLS + tx];
    if (row + ty < NNODES) out[(size_t)(row + ty) * NCLS + tx] = acc;
}

// ---------------- launch ----------------

extern "C" void kernel_launch(void* const* d_in, const int* in_sizes, int n_in,
                              void* d_out, int out_size, void* d_ws, size_t ws_size,
                              hipStream_t stream) {
    const float* x  = (const float*)d_in[0];
    const void*  ei = d_in[1];
    const float* Wq1 = (const float*)d_in[2],  *bq1 = (const float*)d_in[3];
    const float* Wk1 = (const float*)d_in[4],  *bk1 = (const float*)d_in[5];
    const float* Wv1 = (const float*)d_in[6],  *bv1 = (const float*)d_in[7];
    const float* Ws1 = (const float*)d_in[8],  *bs1 = (const float*)d_in[9];
    const float* Wq2 = (const float*)d_in[10], *bq2 = (const float*)d_in[11];
    const float* Wk2 = (const float*)d_in[12], *bk2 = (const float*)d_in[13];
    const float* Wv2 = (const float*)d_in[14], *bv2 = (const float*)d_in[15];
    const float* Ws2 = (const float*)d_in[16], *bs2 = (const float*)d_in[17];
    const float* Wlin = (const float*)d_in[18], *blin = (const float*)d_in[19];
    float* out = (float*)d_out;

    const size_t BUFE = (size_t)NNODES * FD;        // 12.8M floats
    float* Qb = (float*)d_ws;                       // Q / layer output (fp32)
    float* Cb = Qb + BUFE;                          // layer-2 Q / output (fp32)
    float* Sb = Cb + BUFE;                          // SKIP (fp32, reused per layer)
    unsigned short* KVb = (unsigned short*)(Sb + BUFE);   // N x 256 bf16 interleaved K/V
    int* row_ptr    = (int*)(KVb + (size_t)NNODES * 256); // N+1
    int* cursor     = row_ptr + (NNODES + 1);       // N
    int* src_sorted = cursor + NNODES;              // E
    int* flag_is32  = src_sorted + NEDGES;          // 1
    int* blk_tot    = flag_is32 + 1;                // NB_SCAN
    int* blk_off    = blk_tot + NB_SCAN;            // NB_SCAN
    uintptr_t pal = ((uintptr_t)(blk_off + NB_SCAN) + 15) & ~(uintptr_t)15;
    short* Whi = (short*)pal;                       // 8 slots x 16384 bf16 = 256 KB
    short* Wlo = Whi + 8 * 16384;

    // ---- weight packing (tiny) ----
    const float* Ws[8] = {Wq1, Wk1, Wv1, Ws1, Wq2, Wk2, Wv2, Ws2};
    for (int s = 0; s < 8; s++)
        pack_w<<<32, 64, 0, stream>>>(Ws[s], Whi, Wlo, s);

    // ---- dtype detect + CSR build ----
    hipMemsetAsync(row_ptr, 0, (NNODES + 1) * sizeof(int), stream);
    hipMemsetAsync(flag_is32, 0, sizeof(int), stream);
    detect_kernel<<<16, 256, 0, stream>>>((const long long*)ei, flag_is32);
    hist_kernel<<<(NEDGES + 255) / 256, 256, 0, stream>>>(ei, flag_is32, row_ptr);
    scan_blk<<<NB_SCAN, 1024, 0, stream>>>(row_ptr, cursor, blk_tot);
    scan_tops<<<1, 128, 0, stream>>>(blk_tot, blk_off);
    scan_add<<<NB_SCAN, 1024, 0, stream>>>(row_ptr, cursor, blk_off);
    fill_kernel<<<(NEDGES + 255) / 256, 256, 0, stream>>>(ei, flag_is32, cursor, src_sorted);

    int pgrid = (NNODES + 63) / 64;

    // ---- layer 1 ----
    proj_gemm_mfma<<<pgrid, 256, 0, stream>>>(x, Whi, Wlo,
        bq1, bk1, bv1, bs1, Qb, KVb, Sb);
    agg_kernel<<<(NNODES + 3) / 4, 256, 0, stream>>>(Qb, KVb, Sb, Qb,
        row_ptr, src_sorted, 1);

    // ---- layer 2 ----
    proj_gemm_mfma<<<pgrid, 256, 0, stream>>>(Qb, Whi + 4 * 16384, Wlo + 4 * 16384,
        bq2, bk2, bv2, bs2, Cb, KVb, Sb);
    agg_kernel<<<(NNODES + 3) / 4, 256, 0, stream>>>(Cb, KVb, Sb, Cb,
        row_ptr, src_sorted, 0);

    // ---- classifier ----
    final_lin<<<(NNODES + 7) / 8, dim3(NCLS, 8), 0, stream>>>(Cb, Wlin, blin, out);
}

// Round 12
// 804.554 us; speedup vs baseline: 2.2687x; 1.1270x over previous
//
#include <hip/hip_runtime.h>
#include <math.h>

#define NNODES 100000
#define NEDGES 1600000
#define FD 128
#define NCLS 40
#define NB_SCAN ((NNODES + 1023) / 1024)   // 98
#define PGRID ((NNODES + 63) / 64)         // 1563 proj blocks
#define FGRID ((NEDGES + 255) / 256)       // 6250 fill/hist blocks

typedef __attribute__((ext_vector_type(8))) short short8v;   // 8 x bf16 (4 VGPR)
typedef __attribute__((ext_vector_type(4))) float f32x4;

__device__ __forceinline__ unsigned short f32_to_bf16_rne(float f) {
    unsigned int u = __float_as_uint(f);
    unsigned int r = u + 0x7fff + ((u >> 16) & 1);
    return (unsigned short)(r >> 16);
}
__device__ __forceinline__ float bf16_to_f32(unsigned short h) {
    return __uint_as_float(((unsigned int)h) << 16);
}

// ---- per-block edge-dtype self-detection (int64 vs harness-narrowed int32) ----
// Wave 0 samples 64 strided int64-slots (all < NEDGES slots: in-bounds under both
// layouts). int64 layout -> every sample in [0,N); int32 layout -> some sample has a
// nonzero high word (P(miss) ~ 0). Ballot is wave-uniform, verdict via LDS.

__device__ __forceinline__ int detect_is32_block(const void* eiv, int* s_flag) {
    if (threadIdx.x < 64) {
        const long long* p = (const long long*)eiv;
        long long v = p[(size_t)threadIdx.x * (NEDGES / 64)];
        unsigned long long bad = __ballot(v < 0 || v >= (long long)NNODES);
        if (threadIdx.x == 0) *s_flag = (bad != 0ULL);
    }
    __syncthreads();
    return *s_flag;
}

__device__ __forceinline__ void load_edge(const void* eiv, int is32, int e, int& s, int& d) {
    if (is32) {
        const int* p = (const int*)eiv;
        s = p[e]; d = p[NEDGES + e];
    } else {
        const long long* p = (const long long*)eiv;
        s = (int)p[e]; d = (int)p[NEDGES + e];
    }
}

// ---------------- CSR build (dst-sorted adjacency), built once per call ----------------

__global__ __launch_bounds__(256) void hist_kernel(const void* __restrict__ eiv,
                                                   int* __restrict__ row_ptr) {
    __shared__ int sflag;
    int is32 = detect_is32_block(eiv, &sflag);
    int e = blockIdx.x * blockDim.x + threadIdx.x;
    if (e < NEDGES) {
        int s, d;
        load_edge(eiv, is32, e, s, d);
        atomicAdd(&row_ptr[d + 1], 1);
    }
}

// 98 blocks: local inclusive scan of 1024 counts
__global__ __launch_bounds__(1024) void scan_blk(int* __restrict__ row_ptr,
                                                 int* __restrict__ cursor,
                                                 int* __restrict__ blk_tot) {
    __shared__ int wtot[16];
    __shared__ int woff[16];
    int t = threadIdx.x, lane = t & 63, wid = t >> 6;
    int i = blockIdx.x * 1024 + t;
    int c = (i < NNODES) ? row_ptr[1 + i] : 0;
    int x = c;
    #pragma unroll
    for (int off = 1; off < 64; off <<= 1) {
        int y = __shfl_up(x, off, 64);
        if (lane >= off) x += y;
    }
    if (lane == 63) wtot[wid] = x;
    __syncthreads();
    if (t < 16) {
        int v = wtot[t];
        #pragma unroll
        for (int off = 1; off < 16; off <<= 1) {
            int y = __shfl_up(v, off, 64);
            if (t >= off) v += y;
        }
        woff[t] = v;
    }
    __syncthreads();
    int excl = (wid == 0) ? 0 : woff[wid - 1];
    int incl = x + excl;
    if (i < NNODES) {
        row_ptr[1 + i] = incl;
        cursor[i]      = incl - c;
    }
    if (t == 0) blk_tot[blockIdx.x] = woff[15];
}

// 1 block x 128: exclusive scan of the 98 block totals.
__global__ void scan_tops(const int* __restrict__ blk_tot, int* __restrict__ blk_off) {
    __shared__ int s[128];
    int t = threadIdx.x;
    int c0 = (t < NB_SCAN) ? blk_tot[t] : 0;
    s[t] = c0;
    __syncthreads();
    for (int d = 1; d < 128; d <<= 1) {
        int v = (t >= d) ? s[t - d] : 0;
        __syncthreads();
        s[t] += v;
        __syncthreads();
    }
    if (t < NB_SCAN) blk_off[t] = s[t] - c0;
}

// 98 blocks: add block offsets.
__global__ __launch_bounds__(1024) void scan_add(int* __restrict__ row_ptr,
                                                 int* __restrict__ cursor,
                                                 const int* __restrict__ blk_off) {
    int i = blockIdx.x * 1024 + threadIdx.x;
    if (i < NNODES) {
        int o = blk_off[blockIdx.x];
        row_ptr[1 + i] += o;
        cursor[i]      += o;
    }
}

// ---------------- W pack: all 8 slots in one launch ----------------
// packed[slot][ct][kk][lane][j] = W[kk*32 + (lane>>4)*8 + j][ct*16 + (lane&15)]

__global__ void pack_all(
    const float* __restrict__ W0, const float* __restrict__ W1,
    const float* __restrict__ W2, const float* __restrict__ W3,
    const float* __restrict__ W4, const float* __restrict__ W5,
    const float* __restrict__ W6, const float* __restrict__ W7,
    short* __restrict__ Whi, short* __restrict__ Wlo)
{
    int slot = blockIdx.x >> 5;        // 0..7
    int ctkk = blockIdx.x & 31;        // ct*4+kk
    const float* W = (slot == 0) ? W0 : (slot == 1) ? W1 : (slot == 2) ? W2 :
                     (slot == 3) ? W3 : (slot == 4) ? W4 : (slot == 5) ? W5 :
                     (slot == 6) ? W6 : W7;
    int lane = threadIdx.x;            // 64
    int ct = ctkk >> 2, kk = ctkk & 3;
    int col = ct * 16 + (lane & 15);
    int k0 = kk * 32 + (lane >> 4) * 8;
    short8v h, l;
    #pragma unroll
    for (int j = 0; j < 8; j++) {
        float v = W[(size_t)(k0 + j) * FD + col];
        unsigned short hh = f32_to_bf16_rne(v);
        float rem = v - bf16_to_f32(hh);
        h[j] = (short)hh;
        l[j] = (short)f32_to_bf16_rne(rem);
    }
    size_t o = ((size_t)slot * 32 + ctkk) * 512 + (size_t)lane * 8;
    *(short8v*)(Whi + o) = h;
    *(short8v*)(Wlo + o) = l;
}

// ---------------- proj body: fused 4-projection GEMM via bf16 MFMA, fp32-split 3-pass ----
// Outputs: pt0 -> Q (fp32), pt1 -> K (bf16, KV even slots), pt2 -> V (bf16, KV odd slots),
// pt3 -> SKIP (fp32). KV layout: kv[row][2e] = k_e, kv[row][2e+1] = v_e (interleaved).

__device__ __forceinline__ void proj_body(
    int bx,
    const float* __restrict__ X,
    const short* __restrict__ Whi, const short* __restrict__ Wlo,
    const float* __restrict__ b0, const float* __restrict__ b1,
    const float* __restrict__ b2, const float* __restrict__ b3,
    float* __restrict__ Q, unsigned short* __restrict__ KV, float* __restrict__ SKIP)
{
    int wid = threadIdx.x >> 6, lane = threadIdx.x & 63;
    int rowbase = bx * 64 + wid * 16;
    int r = lane & 15, q = lane >> 4;
    int row = rowbase + r;

    short8v xh[4], xl[4];
    if (row < NNODES) {
        const float* xp = X + (size_t)row * FD + q * 8;
        #pragma unroll
        for (int kk = 0; kk < 4; kk++) {
            float4 v0 = *(const float4*)(xp + kk * 32);
            float4 v1 = *(const float4*)(xp + kk * 32 + 4);
            float vv[8] = {v0.x, v0.y, v0.z, v0.w, v1.x, v1.y, v1.z, v1.w};
            #pragma unroll
            for (int j = 0; j < 8; j++) {
                unsigned short h = f32_to_bf16_rne(vv[j]);
                float rem = vv[j] - bf16_to_f32(h);
                xh[kk][j] = (short)h;
                xl[kk][j] = (short)f32_to_bf16_rne(rem);
            }
        }
    } else {
        short8v z = {0, 0, 0, 0, 0, 0, 0, 0};
        #pragma unroll
        for (int kk = 0; kk < 4; kk++) { xh[kk] = z; xl[kk] = z; }
    }

    #pragma unroll
    for (int pt = 0; pt < 4; pt++) {
        const float* bias = (pt == 0) ? b0 : (pt == 1) ? b1 : (pt == 2) ? b2 : b3;
        #pragma unroll
        for (int ct = 0; ct < 8; ct++) {
            const short* wp = Whi + ((size_t)(pt * 8 + ct) * 4) * 512 + (size_t)lane * 8;
            const short* lp = Wlo + ((size_t)(pt * 8 + ct) * 4) * 512 + (size_t)lane * 8;
            f32x4 acc = {0.f, 0.f, 0.f, 0.f};
            #pragma unroll
            for (int kk = 0; kk < 4; kk++) {
                short8v bh = *(const short8v*)(wp + kk * 512);
                short8v bl = *(const short8v*)(lp + kk * 512);
                acc = __builtin_amdgcn_mfma_f32_16x16x32_bf16(xh[kk], bh, acc, 0, 0, 0);
                acc = __builtin_amdgcn_mfma_f32_16x16x32_bf16(xl[kk], bh, acc, 0, 0, 0);
                acc = __builtin_amdgcn_mfma_f32_16x16x32_bf16(xh[kk], bl, acc, 0, 0, 0);
            }
            float bb = bias[ct * 16 + r];
            int e = ct * 16 + r;
            #pragma unroll
            for (int j = 0; j < 4; j++) {
                int ro = rowbase + q * 4 + j;          // D: col=lane&15, row=(lane>>4)*4+j
                if (ro < NNODES) {
                    float val = acc[j] + bb;
                    if (pt == 0)      Q[(size_t)ro * FD + e] = val;
                    else if (pt == 1) KV[(size_t)ro * 256 + 2 * e]     = f32_to_bf16_rne(val);
                    else if (pt == 2) KV[(size_t)ro * 256 + 2 * e + 1] = f32_to_bf16_rne(val);
                    else              SKIP[(size_t)ro * FD + e] = val;
                }
            }
        }
    }
}

// standalone proj (layer 2)
__global__ __launch_bounds__(256) void proj_gemm_mfma(
    const float* __restrict__ X,
    const short* __restrict__ Whi, const short* __restrict__ Wlo,
    const float* __restrict__ b0, const float* __restrict__ b1,
    const float* __restrict__ b2, const float* __restrict__ b3,
    float* __restrict__ Q, unsigned short* __restrict__ KV, float* __restrict__ SKIP)
{
    proj_body(blockIdx.x, X, Whi, Wlo, b0, b1, b2, b3, Q, KV, SKIP);
}

// ---- fused: blocks [0,PGRID) run proj layer 1; blocks [PGRID, PGRID+FGRID) run fill ----
// fill (atomic/scatter latency-bound, ~0% VALU) hides under proj (compute-bound).
// Independent data: proj reads x/W, writes Q/KV/SKIP; fill reads ei/cursor, writes src_sorted.

__global__ __launch_bounds__(256) void proj1_fill(
    const float* __restrict__ X,
    const short* __restrict__ Whi, const short* __restrict__ Wlo,
    const float* __restrict__ b0, const float* __restrict__ b1,
    const float* __restrict__ b2, const float* __restrict__ b3,
    float* __restrict__ Q, unsigned short* __restrict__ KV, float* __restrict__ SKIP,
    const void* __restrict__ eiv, int* __restrict__ cursor, int* __restrict__ src_sorted)
{
    if (blockIdx.x < PGRID) {
        proj_body(blockIdx.x, X, Whi, Wlo, b0, b1, b2, b3, Q, KV, SKIP);
    } else {
        __shared__ int sflag;
        int is32 = detect_is32_block(eiv, &sflag);
        int e = (blockIdx.x - PGRID) * 256 + threadIdx.x;
        if (e < NEDGES) {
            int s, d;
            load_edge(eiv, is32, e, s, d);
            int pos = atomicAdd(&cursor[d], 1);
            src_sorted[pos] = s;
        }
    }
}

// ---------------- per-node softmax aggregation: 2 edges/wave, 4 channels/lane ----------------

__global__ __launch_bounds__(256) void agg_kernel(
    const float* __restrict__ Q, const unsigned short* __restrict__ KV,
    const float* __restrict__ SKIP, float* __restrict__ OUT,
    const int* __restrict__ row_ptr, const int* __restrict__ src_sorted, int apply_elu)
{
    int wid  = threadIdx.x >> 6;
    int lane = threadIdx.x & 63;
    int half = lane >> 5;
    int sub  = lane & 31;
    int node = blockIdx.x * 4 + wid;
    if (node >= NNODES) return;
    size_t rb = (size_t)node * FD;

    float4 q4 = *(const float4*)(Q + rb + sub * 4);
    q4.x *= 0.125f; q4.y *= 0.125f; q4.z *= 0.125f; q4.w *= 0.125f;   // 1/sqrt(64)

    float s = 0.f;
    float4 acc = make_float4(0.f, 0.f, 0.f, 0.f);
    int e0 = row_ptr[node], e1 = row_ptr[node + 1];
    const uint4* KV4 = (const uint4*)KV;    // 8 shorts per uint4

#define PAIR_UPD(EID)                                                          \
    {                                                                          \
        int eid = (EID);                                                       \
        int valid = eid < e1;                                                  \
        int j = src_sorted[valid ? eid : e1 - 1];                              \
        uint4 wv = KV4[(size_t)j * 32 + sub];                                  \
        float kx = __uint_as_float(wv.x << 16);                                \
        float vx = __uint_as_float(wv.x & 0xffff0000u);                        \
        float ky = __uint_as_float(wv.y << 16);                                \
        float vy = __uint_as_float(wv.y & 0xffff0000u);                        \
        float kz = __uint_as_float(wv.z << 16);                                \
        float vz = __uint_as_float(wv.z & 0xffff0000u);                        \
        float kw = __uint_as_float(wv.w << 16);                                \
        float vw = __uint_as_float(wv.w & 0xffff0000u);                        \
        float p = q4.x * kx + q4.y * ky + q4.z * kz + q4.w * kw;               \
        p += __shfl_xor(p, 1, 64);                                             \
        p += __shfl_xor(p, 2, 64);                                             \
        p += __shfl_xor(p, 4, 64);                                             \
        p += __shfl_xor(p, 8, 64);         /* per-16-lane group = head sum */  \
        float w = valid ? __expf(p) : 0.f;                                     \
        s += w;                                                                \
        acc.x += w * vx; acc.y += w * vy;                                      \
        acc.z += w * vz; acc.w += w * vw;                                      \
    }

    for (int base = e0; base < e1; base += 4) {
        PAIR_UPD(base + half)
        PAIR_UPD(base + 2 + half)
    }
#undef PAIR_UPD

    // combine the two half-streams
    s += __shfl_xor(s, 32, 64);
    acc.x += __shfl_xor(acc.x, 32, 64);
    acc.y += __shfl_xor(acc.y, 32, 64);
    acc.z += __shfl_xor(acc.z, 32, 64);
    acc.w += __shfl_xor(acc.w, 32, 64);

    if (half == 0) {
        float r = 1.f / (s + 1e-16f);
        float4 sk = *(const float4*)(SKIP + rb + sub * 4);
        float ox = acc.x * r + sk.x;
        float oy = acc.y * r + sk.y;
        float oz = acc.z * r + sk.z;
        float ow = acc.w * r + sk.w;
        if (apply_elu) {
            ox = (ox > 0.f) ? ox : (__expf(ox) - 1.f);
            oy = (oy > 0.f) ? oy : (__expf(oy) - 1.f);
            oz = (oz > 0.f) ? oz : (__expf(oz) - 1.f);
            ow = (ow > 0.f) ? ow : (__expf(ow) - 1.f);
        }
        *(float4*)(OUT + rb + sub * 4) = make_float4(ox, oy, oz, ow);
    }
}

// ---------------- final classifier: out = H @ Wlin + blin  ([N,128] @ [128,40]) ----------------

__global__ void final_lin(const float* __restrict__ H, const float* __restrict__ Wl,
                          const float* __restrict__ bl, float* __restrict__ out)
{
    __shared__ float ws[FD * NCLS];    // 20 KB
    __shared__ float xs[8][FD + 1];
    int tx = threadIdx.x;              // 0..39 (col)
    int ty = threadIdx.y;              // 0..7  (row)
    int t = ty * NCLS + tx;
    for (int i = t; i < FD * NCLS; i += 320) ws[i] = Wl[i];
    int row = blockIdx.x * 8;
    for (int i = t; i < 8 * FD; i += 320) {
        int r = i >> 7, c = i & 127;
        xs[r][c] = (row + r < NNODES) ? H[(size_t)(row + r) * FD + c] : 0.f;
    }
    __syncthreads();
    float acc = bl[tx];
    #pragma unroll
    for (int k = 0; k < FD; k++) acc += xs[ty][k] * ws[k * NCLS + tx];
    if (row + ty < NNODES) out[(size_t)(row + ty) * NCLS + tx] = acc;
}

// ---------------- launch ----------------

extern "C" void kernel_launch(void* const* d_in, const int* in_sizes, int n_in,
                              void* d_out, int out_size, void* d_ws, size_t ws_size,
                              hipStream_t stream) {
    const float* x  = (const float*)d_in[0];
    const void*  ei = d_in[1];
    const float* Wq1 = (const float*)d_in[2],  *bq1 = (const float*)d_in[3];
    const float* Wk1 = (const float*)d_in[4],  *bk1 = (const float*)d_in[5];
    const float* Wv1 = (const float*)d_in[6],  *bv1 = (const float*)d_in[7];
    const float* Ws1 = (const float*)d_in[8],  *bs1 = (const float*)d_in[9];
    const float* Wq2 = (const float*)d_in[10], *bq2 = (const float*)d_in[11];
    const float* Wk2 = (const float*)d_in[12], *bk2 = (const float*)d_in[13];
    const float* Wv2 = (const float*)d_in[14], *bv2 = (const float*)d_in[15];
    const float* Ws2 = (const float*)d_in[16], *bs2 = (const float*)d_in[17];
    const float* Wlin = (const float*)d_in[18], *blin = (const float*)d_in[19];
    float* out = (float*)d_out;

    const size_t BUFE = (size_t)NNODES * FD;        // 12.8M floats
    float* Qb = (float*)d_ws;                       // Q / layer output (fp32)
    float* Cb = Qb + BUFE;                          // layer-2 Q / output (fp32)
    float* Sb = Cb + BUFE;                          // SKIP (fp32, reused per layer)
    unsigned short* KVb = (unsigned short*)(Sb + BUFE);   // N x 256 bf16 interleaved K/V
    int* row_ptr    = (int*)(KVb + (size_t)NNODES * 256); // N+1
    int* cursor     = row_ptr + (NNODES + 1);       // N
    int* src_sorted = cursor + NNODES;              // E
    int* blk_tot    = src_sorted + NEDGES;          // NB_SCAN
    int* blk_off    = blk_tot + NB_SCAN;            // NB_SCAN
    uintptr_t pal = ((uintptr_t)(blk_off + NB_SCAN) + 15) & ~(uintptr_t)15;
    short* Whi = (short*)pal;                       // 8 slots x 16384 bf16 = 256 KB
    short* Wlo = Whi + 8 * 16384;

    // ---- weight packing (one launch) + CSR histogram ----
    hipMemsetAsync(row_ptr, 0, (NNODES + 1) * sizeof(int), stream);
    pack_all<<<256, 64, 0, stream>>>(Wq1, Wk1, Wv1, Ws1, Wq2, Wk2, Wv2, Ws2, Whi, Wlo);
    hist_kernel<<<FGRID, 256, 0, stream>>>(ei, row_ptr);
    scan_blk<<<NB_SCAN, 1024, 0, stream>>>(row_ptr, cursor, blk_tot);
    scan_tops<<<1, 128, 0, stream>>>(blk_tot, blk_off);
    scan_add<<<NB_SCAN, 1024, 0, stream>>>(row_ptr, cursor, blk_off);

    // ---- layer 1 proj fused with CSR fill (independent work, fill hides under compute) ----
    proj1_fill<<<PGRID + FGRID, 256, 0, stream>>>(x, Whi, Wlo,
        bq1, bk1, bv1, bs1, Qb, KVb, Sb, ei, cursor, src_sorted);
    agg_kernel<<<(NNODES + 3) / 4, 256, 0, stream>>>(Qb, KVb, Sb, Qb,
        row_ptr, src_sorted, 1);

    // ---- layer 2 ----
    proj_gemm_mfma<<<PGRID, 256, 0, stream>>>(Qb, Whi + 4 * 16384, Wlo + 4 * 16384,
        bq2, bk2, bv2, bs2, Cb, KVb, Sb);
    agg_kernel<<<(NNODES + 3) / 4, 256, 0, stream>>>(Cb, KVb, Sb, Cb,
        row_ptr, src_sorted, 0);

    // ---- classifier ----
    final_lin<<<(NNODES + 7) / 8, dim3(NCLS, 8), 0, stream>>>(Cb, Wlin, blin, out);
}